// Round 9
// baseline (458.496 us; speedup 1.0000x reference)
//
#include <hip/hip_runtime.h>
#include <hip/hip_bf16.h>
#include <hip/hip_fp16.h>

#define N_NODES 131072
#define N_PER   1024
#define NGRAPH  128
#define N_EDGES 2097152
#define EPG     16384     // edges per graph
#define KSP     30
#define HID     128
#define IN_CH   14
#define OUT_DIM 4

typedef __attribute__((ext_vector_type(8))) short    v8s;
typedef __attribute__((ext_vector_type(8))) _Float16 v8h;
typedef __attribute__((ext_vector_type(4))) float    v4f;

__device__ inline v8h as_h(v8s s){ union { v8s s; v8h h; } u; u.s = s; return u.h; }

// fp32 -> f16 hi + f16 lo (lo pre-scaled by 2^12). hi never denormal.
#define LOSCALE 4096.0f
#define INV_LOSCALE (1.0f/4096.0f)
__device__ inline void f2split(float v, ushort& hi, ushort& lo){
  float av = fabsf(v);
  __half h = (av < 6.103515625e-05f) ? __ushort_as_half((ushort)0) : __float2half(v);
  hi = __half_as_ushort(h);
  lo = __half_as_ushort(__float2half((v - __half2float(h)) * LOSCALE));
}
__device__ inline float f2join(ushort hi, ushort lo){
  return __half2float(__ushort_as_half(hi)) + __half2float(__ushort_as_half(lo)) * INV_LOSCALE;
}

// ---------------- fused per-graph CSR build (count+scan+scatter in LDS) ----------------
__global__ __launch_bounds__(1024) void k_csr(const int* __restrict__ src, const int* __restrict__ dst,
    ushort* __restrict__ csr, int* __restrict__ row_ptr, float* __restrict__ dinv){
  __shared__ ushort lcsr[EPG];     // 32 KB
  __shared__ int ldeg[N_PER];
  __shared__ int lrp[N_PER];
  __shared__ int lcur[N_PER];
  int g = blockIdx.x, t = threadIdx.x;
  int base = g*EPG;
  ldeg[t] = 0;
  __syncthreads();
  #pragma unroll
  for (int r = 0; r < EPG/1024; ++r)
    atomicAdd(&ldeg[dst[base + r*1024 + t] & (N_PER-1)], 1);
  __syncthreads();
  int d = ldeg[t];
  lrp[t] = d;
  __syncthreads();
  for (int ofs = 1; ofs < N_PER; ofs <<= 1){
    int v = lrp[t];
    int add = (t >= ofs) ? lrp[t-ofs] : 0;
    __syncthreads();
    lrp[t] = v + add;
    __syncthreads();
  }
  int ex = lrp[t] - d;               // exclusive prefix
  lcur[t] = ex;
  row_ptr[g*N_PER + t] = base + ex;
  dinv[g*N_PER + t] = d > 0 ? 1.0f/(float)d : 0.0f;
  if (g == NGRAPH-1 && t == 0) row_ptr[N_NODES] = N_EDGES;
  __syncthreads();
  #pragma unroll
  for (int r = 0; r < EPG/1024; ++r){
    int e = base + r*1024 + t;
    int dl = dst[e] & (N_PER-1);
    int pos = atomicAdd(&lcur[dl], 1);
    lcsr[pos] = (ushort)(src[e] & (N_PER-1));
  }
  __syncthreads();
  uint* gout = (uint*)(csr + base);
  const uint* lin = (const uint*)lcsr;
  #pragma unroll
  for (int r = 0; r < EPG/2048; ++r)
    gout[r*1024 + t] = lin[r*1024 + t];
}

// ---------------- prep: pack x / W into MFMA-fragment layouts (f16 hi/lo planes) ----------------
__global__ __launch_bounds__(256) void k_pack_x(const float* __restrict__ x,
                                                ushort* __restrict__ xhi, ushort* __restrict__ xlo){
  int i = blockIdx.x*256 + threadIdx.x;          // N_NODES*32
  int n = i >> 5, k = i & 31;
  float v = (k < IN_CH) ? x[n*IN_CH + k] : 0.0f;
  int dst = (n >> 4)*512 + ((k >> 3)*16 + (n & 15))*8 + (k & 7);
  ushort hi, lo; f2split(v, hi, lo);
  xhi[dst] = hi; xlo[dst] = lo;
}

__global__ __launch_bounds__(256) void k_pack_w(const float* __restrict__ wl, const float* __restrict__ wr,
    ushort* __restrict__ wlh, ushort* __restrict__ wll,
    ushort* __restrict__ wrh, ushort* __restrict__ wrl, int KC, int kin){
  int i = blockIdx.x*256 + threadIdx.x;
  int Kp = KC*32;
  if (i >= 256*Kp) return;
  int which = i / (128*Kp);
  int r = (i / Kp) & 127;
  int k = i % Kp;
  const float* w = which ? wr : wl;
  float v = (k < kin) ? w[r*kin + k] : 0.0f;
  ushort hi, lo; f2split(v, hi, lo);
  int dst = ((r >> 4)*KC + (k >> 5))*512 + ((((k & 31) >> 3))*16 + (r & 15))*8 + (k & 7);
  if (which){ wrh[dst] = hi; wrl[dst] = lo; }
  else      { wlh[dst] = hi; wll[dst] = lo; }
}

__global__ __launch_bounds__(256) void k_transpose_cw(const float* __restrict__ cw, float* __restrict__ cwT){
  int e = blockIdx.x*256 + threadIdx.x;          // 32*128*5
  if (e < 32*HID*5){
    int o = e / 640, rem = e % 640;
    cwT[rem*32 + o] = cw[e];
  }
}

// ---------------- gather: M[i] = mean_{j->i} H[j] (frag layout in/out) ----------------
#define FXS 262144.0f
__global__ __launch_bounds__(1024) void k_gather(
    const ushort* __restrict__ Hhi, const ushort* __restrict__ Hlo,
    ushort* __restrict__ Mhi, ushort* __restrict__ Mlo,
    const int* __restrict__ row_ptr, const ushort* __restrict__ csr,
    const float* __restrict__ dinv, int KC){
  __shared__ int ldsI[N_PER*20];                 // 80 KB
  int P = KC*2;
  int g = blockIdx.x / P, p = blockIdx.x % P;
  int kc = p >> 1, half = p & 1;
  int t = threadIdx.x;
  for (int it = t; it < 16384; it += 1024){
    int Tl = it >> 8, e = it & 255;
    int idx = (((g*64 + Tl)*KC + kc) << 9) + (half << 8) + e;
    float v = f2join(Hhi[idx], Hlo[idx]);
    int l = e >> 3, j = e & 7;
    int m = l & 15, qh = l >> 4;
    ldsI[(Tl*16 + m)*20 + qh*8 + j] = __float2int_rn(v*FXS);
  }
  __syncthreads();
  int o2 = t & 1, ns = t >> 1;
  #pragma unroll
  for (int rep = 0; rep < 2; ++rep){
    int n = ns + rep*512;
    int node = g*N_PER + n;
    int s = row_ptr[node], e = row_ptr[node+1];
    int a0=0,a1=0,a2=0,a3=0,a4=0,a5=0,a6=0,a7=0;
    int j2 = s;
    for (; j2 + 2 <= e; j2 += 2){
      int la = csr[j2];
      int lb = csr[j2+1];
      const int4* ra = (const int4*)&ldsI[la*20 + o2*8];
      const int4* rb = (const int4*)&ldsI[lb*20 + o2*8];
      int4 x0 = ra[0], x1 = ra[1], y0 = rb[0], y1 = rb[1];
      a0 += x0.x + y0.x; a1 += x0.y + y0.y; a2 += x0.z + y0.z; a3 += x0.w + y0.w;
      a4 += x1.x + y1.x; a5 += x1.y + y1.y; a6 += x1.z + y1.z; a7 += x1.w + y1.w;
    }
    if (j2 < e){
      int la = csr[j2];
      const int4* ra = (const int4*)&ldsI[la*20 + o2*8];
      int4 x0 = ra[0], x1 = ra[1];
      a0 += x0.x; a1 += x0.y; a2 += x0.z; a3 += x0.w;
      a4 += x1.x; a5 += x1.y; a6 += x1.z; a7 += x1.w;
    }
    float di = dinv[node] * (1.0f/FXS);
    float mv[8] = {(float)a0*di,(float)a1*di,(float)a2*di,(float)a3*di,
                   (float)a4*di,(float)a5*di,(float)a6*di,(float)a7*di};
    int q = half*2 + o2;
    int base = (((g*64 + (n >> 4))*KC + kc) << 9) + (q*16 + (n & 15))*8;
    ushort hs[8], ls[8];
    #pragma unroll
    for (int ii = 0; ii < 8; ++ii) f2split(mv[ii], hs[ii], ls[ii]);
    *(ushort4*)&Mhi[base]   = make_ushort4(hs[0],hs[1],hs[2],hs[3]);
    *(ushort4*)&Mhi[base+4] = make_ushort4(hs[4],hs[5],hs[6],hs[7]);
    *(ushort4*)&Mlo[base]   = make_ushort4(ls[0],ls[1],ls[2],ls[3]);
    *(ushort4*)&Mlo[base+4] = make_ushort4(ls[4],ls[5],ls[6],ls[7]);
  }
}

// ---------------- GEMM: h = relu(M@Wl + H@Wr + b), fp16x2 dual-accumulator ----------------
// 256 thr = 4 waves. Block = 64 rows x 128 cols. Wave = 2 row-tiles x 4 col-tiles.
// B staged in 32 KB LDS, software-pipelined (reg-prefetch of B(kc+1) during compute(kc)).
// __launch_bounds__(256,4): 4 blocks/CU (VGPR 80 <= 128, LDS 4x32=128 <= 160 KB) — R8's
// (256,2) capped at 2 blocks/CU and left the kernel latency-bound at 24.7% occupancy.
template<int KCI, int MODE>   // MODE0: f16 hi/lo planes out (KC_out=4). MODE1: f16 hi plane + fp32 key (col 127).
__global__ __launch_bounds__(256, 4) void k_gemm(
    const ushort* __restrict__ Ah1, const ushort* __restrict__ Al1,
    const ushort* __restrict__ Ah2, const ushort* __restrict__ Al2,
    const ushort* __restrict__ wlh, const ushort* __restrict__ wll,
    const ushort* __restrict__ wrh, const ushort* __restrict__ wrl,
    const float* __restrict__ bias, ushort* Hho, ushort* Hlo2, float* key){
  __shared__ ushort smB[4*8*512];                // 32 KB: [region(4)][ct(8)][lane(64)][8]
  int t = threadIdx.x, w = t >> 6, l = t & 63;
  int q = l >> 4, m = l & 15;
  int rtl = (w & 1)*2;                           // local row-tile base (0 or 2)
  int ctb = (w >> 1)*4;                          // col-tile base (0 or 4)
  int t0 = blockIdx.x*4;                         // block = 4 row-tiles (64 rows)
  const ushort* warr[4] = {wlh, wll, wrh, wrl};  // (src,plane) = (0,h),(0,l),(1,h),(1,l)
  v4f acc1[2][4], acc2[2][4];                    // [rr][cc]
  #pragma unroll
  for (int a = 0; a < 2; ++a)
    #pragma unroll
    for (int b = 0; b < 4; ++b){ acc1[a][b] = (v4f){0.f,0.f,0.f,0.f}; acc2[a][b] = (v4f){0.f,0.f,0.f,0.f}; }
  v8s* smv = (v8s*)smB;
  v8s pre[8];
  // prefetch B(kc=0) and commit
  #pragma unroll
  for (int i2 = 0; i2 < 8; ++i2){
    int i = i2*256 + t; int r = i >> 9, e2 = i & 511, ct = e2 >> 6, j = e2 & 63;
    pre[i2] = *(const v8s*)(warr[r] + ((ct*KCI + 0) << 9) + j*8);
  }
  #pragma unroll
  for (int i2 = 0; i2 < 8; ++i2) smv[i2*256 + t] = pre[i2];

  for (int kc = 0; kc < KCI; ++kc){
    __syncthreads();                             // B(kc) visible in LDS
    if (kc + 1 < KCI){
      #pragma unroll
      for (int i2 = 0; i2 < 8; ++i2){
        int i = i2*256 + t; int r = i >> 9, e2 = i & 511, ct = e2 >> 6, j = e2 & 63;
        pre[i2] = *(const v8s*)(warr[r] + ((ct*KCI + kc + 1) << 9) + j*8);
      }
    }
    // A fragments for this wave's 2 row-tiles (8 loads, batched)
    v8h a1h[2], a1l[2], a2h[2], a2l[2];
    #pragma unroll
    for (int rr = 0; rr < 2; ++rr){
      int aoff = (((t0 + rtl + rr)*KCI + kc) << 9) + l*8;
      a1h[rr] = as_h(*(const v8s*)(Ah1 + aoff));
      a1l[rr] = as_h(*(const v8s*)(Al1 + aoff));
      a2h[rr] = as_h(*(const v8s*)(Ah2 + aoff));
      a2l[rr] = as_h(*(const v8s*)(Al2 + aoff));
    }
    #pragma unroll
    for (int cc = 0; cc < 4; ++cc){
      int ct = ctb + cc;
      v8h b0h = as_h(smv[(0*8 + ct)*64 + l]);
      v8h b0l = as_h(smv[(1*8 + ct)*64 + l]);
      v8h b1h = as_h(smv[(2*8 + ct)*64 + l]);
      v8h b1l = as_h(smv[(3*8 + ct)*64 + l]);
      #pragma unroll
      for (int rr = 0; rr < 2; ++rr){
        acc1[rr][cc] = __builtin_amdgcn_mfma_f32_16x16x32_f16(a1h[rr], b0h, acc1[rr][cc], 0, 0, 0);
        acc2[rr][cc] = __builtin_amdgcn_mfma_f32_16x16x32_f16(a1l[rr], b0h, acc2[rr][cc], 0, 0, 0);
        acc2[rr][cc] = __builtin_amdgcn_mfma_f32_16x16x32_f16(a1h[rr], b0l, acc2[rr][cc], 0, 0, 0);
        acc1[rr][cc] = __builtin_amdgcn_mfma_f32_16x16x32_f16(a2h[rr], b1h, acc1[rr][cc], 0, 0, 0);
        acc2[rr][cc] = __builtin_amdgcn_mfma_f32_16x16x32_f16(a2l[rr], b1h, acc2[rr][cc], 0, 0, 0);
        acc2[rr][cc] = __builtin_amdgcn_mfma_f32_16x16x32_f16(a2h[rr], b1l, acc2[rr][cc], 0, 0, 0);
      }
    }
    __syncthreads();                             // all waves done reading B(kc)
    if (kc + 1 < KCI){
      #pragma unroll
      for (int i2 = 0; i2 < 8; ++i2) smv[i2*256 + t] = pre[i2];
    }
  }
  // epilogue: row = (t0+rtl+rr)*16 + q*4 + r, col = (ctb+cc)*16 + m; dest frag KC_out = 4
  #pragma unroll
  for (int cc = 0; cc < 4; ++cc){
    int ct_g = ctb + cc;
    float badd = bias[ct_g*16 + m];
    #pragma unroll
    for (int rr = 0; rr < 2; ++rr){
      int T = t0 + rtl + rr;
      #pragma unroll
      for (int r = 0; r < 4; ++r){
        float v = fmaxf(acc1[rr][cc][r] + acc2[rr][cc][r]*INV_LOSCALE + badd, 0.0f);
        int lane2 = ((ct_g & 1)*2 + (m >> 3))*16 + q*4 + r;
        int didx = ((T*4 + (ct_g >> 1)) << 9) + lane2*8 + (m & 7);
        if (MODE == 0){
          ushort hi, lo; f2split(v, hi, lo);
          Hho[didx] = hi; Hlo2[didx] = lo;
        } else {
          Hho[didx] = __half_as_ushort(__float2half(v));
          if (ct_g == 7 && m == 15) key[T*16 + q*4 + r] = v;   // exact fp32 sort key (ch 127)
        }
      }
    }
  }
}

// ---------------- sort-pool: coalesced fp32 key read ----------------
__global__ __launch_bounds__(1024) void k_sortpool(const float* __restrict__ keyv, int* __restrict__ sel){
  int g = blockIdx.x, t = threadIdx.x;
  __shared__ unsigned long long key[N_PER];
  __shared__ unsigned long long wred[16];
  float v = keyv[g*N_PER + t];                   // post-relu, v >= 0 -> bits monotone
  key[t] = (((unsigned long long)__float_as_uint(v)) << 10) | (unsigned long long)(N_PER-1 - t);
  __syncthreads();
  for (int r = 0; r < KSP; ++r){
    unsigned long long k = key[t];
    #pragma unroll
    for (int ofs = 32; ofs > 0; ofs >>= 1){
      unsigned long long o2 = __shfl_down(k, ofs, 64);
      if (o2 > k) k = o2;
    }
    if ((t & 63) == 0) wred[t >> 6] = k;
    __syncthreads();
    if (t == 0){
      unsigned long long mm = wred[0];
      #pragma unroll
      for (int j = 1; j < 16; ++j) if (wred[j] > mm) mm = wred[j];
      int idx = (N_PER-1) - (int)(mm & 1023ULL);
      sel[g*KSP + r] = idx;
      key[idx] = 0ULL;
    }
    __syncthreads();
  }
}

// ---------------- head: H3 read from f16 hi plane (frag layout, KC=4) ----------------
__global__ __launch_bounds__(256) void k_head(const ushort* __restrict__ Hhi, const int* __restrict__ sel,
    const float* __restrict__ cwT, const float* __restrict__ cb,
    const float* __restrict__ l1w, const float* __restrict__ l1b,
    const float* __restrict__ l2w, const float* __restrict__ l2b,
    float* __restrict__ out){
  __shared__ __align__(16) float toplds[KSP*HID];
  __shared__ float ypart[8][832];
  __shared__ __align__(16) float yv[832];
  __shared__ float zv[HID];
  int g = blockIdx.x, t = threadIdx.x;
  for (int e = t; e < KSP*HID; e += 256){
    int tt = e >> 7, c = e & 127;
    int n = g*N_PER + sel[g*KSP + tt];
    int idx = ((n >> 4)*4 + (c >> 5))*512 + (((c & 31) >> 3)*16 + (n & 15))*8 + (c & 7);
    toplds[e] = __half2float(__ushort_as_half(Hhi[idx]));
  }
  __syncthreads();
  int o = t & 31, cch = t >> 5;
  float acc[26];
  #pragma unroll
  for (int th = 0; th < 26; ++th) acc[th] = 0.0f;
  for (int c = cch*16; c < cch*16 + 16; ++c){
    float tcol[KSP];
    #pragma unroll
    for (int tt = 0; tt < KSP; ++tt) tcol[tt] = toplds[tt*HID + c];
    float w5[5];
    #pragma unroll
    for (int s = 0; s < 5; ++s) w5[s] = cwT[(c*5 + s)*32 + o];
    #pragma unroll
    for (int th = 0; th < 26; ++th){
      float a2 = acc[th];
      #pragma unroll
      for (int s = 0; s < 5; ++s) a2 += tcol[th + s]*w5[s];
      acc[th] = a2;
    }
  }
  #pragma unroll
  for (int th = 0; th < 26; ++th) ypart[cch][o*26 + th] = acc[th];
  __syncthreads();
  for (int idx = t; idx < 832; idx += 256){
    float s2 = 0.0f;
    #pragma unroll
    for (int j = 0; j < 8; ++j) s2 += ypart[j][idx];
    yv[idx] = fmaxf(s2 + cb[idx / 26], 0.0f);
  }
  __syncthreads();
  if (t < HID){
    float a3 = l1b[t];
    const float4* wr4 = (const float4*)&l1w[t*832];
    const float4* yr4 = (const float4*)yv;
    #pragma unroll 4
    for (int k = 0; k < 208; ++k){
      float4 wv = wr4[k]; float4 yq = yr4[k];
      a3 += wv.x*yq.x + wv.y*yq.y + wv.z*yq.z + wv.w*yq.w;
    }
    zv[t] = fmaxf(a3, 0.0f);
  }
  __syncthreads();
  if (t < OUT_DIM){
    float a4 = l2b[t];
    for (int j = 0; j < HID; ++j) a4 += zv[j]*l2w[t*HID + j];
    out[g*OUT_DIM + t] = a4;
  }
}

extern "C" void kernel_launch(void* const* d_in, const int* in_sizes, int n_in,
                              void* d_out, int out_size, void* d_ws, size_t ws_size,
                              hipStream_t stream){
  const float* x   = (const float*)d_in[0];
  const int*   ei  = (const int*)d_in[1];
  const float* wl1 = (const float*)d_in[3];
  const float* b1  = (const float*)d_in[4];
  const float* wr1 = (const float*)d_in[5];
  const float* wl2 = (const float*)d_in[6];
  const float* b2  = (const float*)d_in[7];
  const float* wr2 = (const float*)d_in[8];
  const float* wl3 = (const float*)d_in[9];
  const float* b3  = (const float*)d_in[10];
  const float* wr3 = (const float*)d_in[11];
  const float* cw  = (const float*)d_in[12];
  const float* cb  = (const float*)d_in[13];
  const float* l1w = (const float*)d_in[14];
  const float* l1b = (const float*)d_in[15];
  const float* l2w = (const float*)d_in[16];
  const float* l2b = (const float*)d_in[17];
  float* out = (float*)d_out;
  const int* esrc = ei;
  const int* edst = ei + N_EDGES;

  char* p = (char*)d_ws;
  auto alloc = [&](size_t bytes)->char*{ char* r = p; p += (bytes + 255) & ~(size_t)255; return r; };
  int*    row_ptr = (int*)alloc((size_t)(N_NODES+1)*4);
  float*  dinv    = (float*)alloc((size_t)N_NODES*4);
  ushort* csr     = (ushort*)alloc((size_t)N_EDGES*2);
  int*    sel     = (int*)alloc((size_t)NGRAPH*KSP*4);
  float*  cwT     = (float*)alloc((size_t)32*HID*5*4);
  float*  keyv    = (float*)alloc((size_t)N_NODES*4);
  ushort* Xhi     = (ushort*)alloc((size_t)N_NODES*32*2);   // 8.4 MB
  ushort* Xlo     = (ushort*)alloc((size_t)N_NODES*32*2);
  ushort* Mhi     = (ushort*)alloc((size_t)N_NODES*HID*2);  // 33.5 MB
  ushort* Mlo     = (ushort*)alloc((size_t)N_NODES*HID*2);
  ushort* Hhi     = (ushort*)alloc((size_t)N_NODES*HID*2);
  ushort* Hlo     = (ushort*)alloc((size_t)N_NODES*HID*2);
  ushort* w1lh = (ushort*)alloc(512*8*2);  ushort* w1ll = (ushort*)alloc(512*8*2);
  ushort* w1rh = (ushort*)alloc(512*8*2);  ushort* w1rl = (ushort*)alloc(512*8*2);
  ushort* w2lh = (ushort*)alloc(512*32*2); ushort* w2ll = (ushort*)alloc(512*32*2);
  ushort* w2rh = (ushort*)alloc(512*32*2); ushort* w2rl = (ushort*)alloc(512*32*2);
  ushort* w3lh = (ushort*)alloc(512*32*2); ushort* w3ll = (ushort*)alloc(512*32*2);
  ushort* w3rh = (ushort*)alloc(512*32*2); ushort* w3rl = (ushort*)alloc(512*32*2);

  k_csr<<<NGRAPH, 1024, 0, stream>>>(esrc, edst, csr, row_ptr, dinv);

  k_pack_x<<<(N_NODES*32)/256, 256, 0, stream>>>(x, Xhi, Xlo);
  k_pack_w<<<(256*32)/256, 256, 0, stream>>>(wl1, wr1, w1lh, w1ll, w1rh, w1rl, 1, IN_CH);
  k_pack_w<<<(256*128)/256, 256, 0, stream>>>(wl2, wr2, w2lh, w2ll, w2rh, w2rl, 4, 128);
  k_pack_w<<<(256*128)/256, 256, 0, stream>>>(wl3, wr3, w3lh, w3ll, w3rh, w3rl, 4, 128);
  k_transpose_cw<<<(32*HID*5 + 255)/256, 256, 0, stream>>>(cw, cwT);

  const int GB = N_NODES/64;       // 2048 gemm blocks (4 row-tiles each)

  // layer 1: M1 = mean(x_nb); h1 = relu(M1@Wl1 + x@Wr1 + b1)  (K padded to 32)
  k_gather<<<NGRAPH*2, 1024, 0, stream>>>(Xhi, Xlo, Mhi, Mlo, row_ptr, csr, dinv, 1);
  k_gemm<1,0><<<GB, 256, 0, stream>>>(Mhi, Mlo, Xhi, Xlo,
      w1lh, w1ll, w1rh, w1rl, b1, Hhi, Hlo, nullptr);
  // layer 2 (in-place h: block reads only its own rows as A before its epilogue writes)
  k_gather<<<NGRAPH*8, 1024, 0, stream>>>(Hhi, Hlo, Mhi, Mlo, row_ptr, csr, dinv, 4);
  k_gemm<4,0><<<GB, 256, 0, stream>>>(Mhi, Mlo, Hhi, Hlo,
      w2lh, w2ll, w2rh, w2rl, b2, Hhi, Hlo, nullptr);
  // layer 3 -> f16 hi plane (head input) + exact fp32 sort key (channel 127)
  k_gather<<<NGRAPH*8, 1024, 0, stream>>>(Hhi, Hlo, Mhi, Mlo, row_ptr, csr, dinv, 4);
  k_gemm<4,1><<<GB, 256, 0, stream>>>(Mhi, Mlo, Hhi, Hlo,
      w3lh, w3ll, w3rh, w3rl, b3, Hhi, nullptr, keyv);

  k_sortpool<<<NGRAPH, 1024, 0, stream>>>(keyv, sel);
  k_head<<<NGRAPH, 256, 0, stream>>>(Hhi, sel, cwT, cb, l1w, l1b, l2w, l2b, out);
}

// Round 10
// 455.584 us; speedup vs baseline: 1.0064x; 1.0064x over previous
//
#include <hip/hip_runtime.h>
#include <hip/hip_bf16.h>
#include <hip/hip_fp16.h>

#define N_NODES 131072
#define N_PER   1024
#define NGRAPH  128
#define N_EDGES 2097152
#define EPG     16384     // edges per graph
#define KSP     30
#define HID     128
#define IN_CH   14
#define OUT_DIM 4

typedef __attribute__((ext_vector_type(8))) short    v8s;
typedef __attribute__((ext_vector_type(8))) _Float16 v8h;
typedef __attribute__((ext_vector_type(4))) float    v4f;

__device__ inline v8h as_h(v8s s){ union { v8s s; v8h h; } u; u.s = s; return u.h; }

// fp32 -> f16 hi + f16 lo (lo pre-scaled by 2^12). hi never denormal.
#define LOSCALE 4096.0f
#define INV_LOSCALE (1.0f/4096.0f)
__device__ inline void f2split(float v, ushort& hi, ushort& lo){
  float av = fabsf(v);
  __half h = (av < 6.103515625e-05f) ? __ushort_as_half((ushort)0) : __float2half(v);
  hi = __half_as_ushort(h);
  lo = __half_as_ushort(__float2half((v - __half2float(h)) * LOSCALE));
}
__device__ inline float f2join(ushort hi, ushort lo){
  return __half2float(__ushort_as_half(hi)) + __half2float(__ushort_as_half(lo)) * INV_LOSCALE;
}

// ---------------- fused per-graph CSR build (count+scan+scatter in LDS) ----------------
__global__ __launch_bounds__(1024) void k_csr(const int* __restrict__ src, const int* __restrict__ dst,
    ushort* __restrict__ csr, int* __restrict__ row_ptr, float* __restrict__ dinv){
  __shared__ ushort lcsr[EPG];     // 32 KB
  __shared__ int ldeg[N_PER];
  __shared__ int lrp[N_PER];
  __shared__ int lcur[N_PER];
  int g = blockIdx.x, t = threadIdx.x;
  int base = g*EPG;
  ldeg[t] = 0;
  __syncthreads();
  #pragma unroll
  for (int r = 0; r < EPG/1024; ++r)
    atomicAdd(&ldeg[dst[base + r*1024 + t] & (N_PER-1)], 1);
  __syncthreads();
  int d = ldeg[t];
  lrp[t] = d;
  __syncthreads();
  for (int ofs = 1; ofs < N_PER; ofs <<= 1){
    int v = lrp[t];
    int add = (t >= ofs) ? lrp[t-ofs] : 0;
    __syncthreads();
    lrp[t] = v + add;
    __syncthreads();
  }
  int ex = lrp[t] - d;               // exclusive prefix
  lcur[t] = ex;
  row_ptr[g*N_PER + t] = base + ex;
  dinv[g*N_PER + t] = d > 0 ? 1.0f/(float)d : 0.0f;
  if (g == NGRAPH-1 && t == 0) row_ptr[N_NODES] = N_EDGES;
  __syncthreads();
  #pragma unroll
  for (int r = 0; r < EPG/1024; ++r){
    int e = base + r*1024 + t;
    int dl = dst[e] & (N_PER-1);
    int pos = atomicAdd(&lcur[dl], 1);
    lcsr[pos] = (ushort)(src[e] & (N_PER-1));
  }
  __syncthreads();
  uint* gout = (uint*)(csr + base);
  const uint* lin = (const uint*)lcsr;
  #pragma unroll
  for (int r = 0; r < EPG/2048; ++r)
    gout[r*1024 + t] = lin[r*1024 + t];
}

// ---------------- prep: pack x / W into MFMA-fragment layouts (f16 hi/lo planes) ----------------
__global__ __launch_bounds__(256) void k_pack_x(const float* __restrict__ x,
                                                ushort* __restrict__ xhi, ushort* __restrict__ xlo){
  int i = blockIdx.x*256 + threadIdx.x;          // N_NODES*32
  int n = i >> 5, k = i & 31;
  float v = (k < IN_CH) ? x[n*IN_CH + k] : 0.0f;
  int dst = (n >> 4)*512 + ((k >> 3)*16 + (n & 15))*8 + (k & 7);
  ushort hi, lo; f2split(v, hi, lo);
  xhi[dst] = hi; xlo[dst] = lo;
}

__global__ __launch_bounds__(256) void k_pack_w(const float* __restrict__ wl, const float* __restrict__ wr,
    ushort* __restrict__ wlh, ushort* __restrict__ wll,
    ushort* __restrict__ wrh, ushort* __restrict__ wrl, int KC, int kin){
  int i = blockIdx.x*256 + threadIdx.x;
  int Kp = KC*32;
  if (i >= 256*Kp) return;
  int which = i / (128*Kp);
  int r = (i / Kp) & 127;
  int k = i % Kp;
  const float* w = which ? wr : wl;
  float v = (k < kin) ? w[r*kin + k] : 0.0f;
  ushort hi, lo; f2split(v, hi, lo);
  int dst = ((r >> 4)*KC + (k >> 5))*512 + ((((k & 31) >> 3))*16 + (r & 15))*8 + (k & 7);
  if (which){ wrh[dst] = hi; wrl[dst] = lo; }
  else      { wlh[dst] = hi; wll[dst] = lo; }
}

__global__ __launch_bounds__(256) void k_transpose_cw(const float* __restrict__ cw, float* __restrict__ cwT){
  int e = blockIdx.x*256 + threadIdx.x;          // 32*128*5
  if (e < 32*HID*5){
    int o = e / 640, rem = e % 640;
    cwT[rem*32 + o] = cw[e];
  }
}

// ---------------- gather: M[i] = mean_{j->i} H[j] (frag layout in/out) ----------------
#define FXS 262144.0f
__global__ __launch_bounds__(1024) void k_gather(
    const ushort* __restrict__ Hhi, const ushort* __restrict__ Hlo,
    ushort* __restrict__ Mhi, ushort* __restrict__ Mlo,
    const int* __restrict__ row_ptr, const ushort* __restrict__ csr,
    const float* __restrict__ dinv, int KC){
  __shared__ int ldsI[N_PER*20];                 // 80 KB
  int P = KC*2;
  int g = blockIdx.x / P, p = blockIdx.x % P;
  int kc = p >> 1, half = p & 1;
  int t = threadIdx.x;
  for (int it = t; it < 16384; it += 1024){
    int Tl = it >> 8, e = it & 255;
    int idx = (((g*64 + Tl)*KC + kc) << 9) + (half << 8) + e;
    float v = f2join(Hhi[idx], Hlo[idx]);
    int l = e >> 3, j = e & 7;
    int m = l & 15, qh = l >> 4;
    ldsI[(Tl*16 + m)*20 + qh*8 + j] = __float2int_rn(v*FXS);
  }
  __syncthreads();
  int o2 = t & 1, ns = t >> 1;
  #pragma unroll
  for (int rep = 0; rep < 2; ++rep){
    int n = ns + rep*512;
    int node = g*N_PER + n;
    int s = row_ptr[node], e = row_ptr[node+1];
    int a0=0,a1=0,a2=0,a3=0,a4=0,a5=0,a6=0,a7=0;
    int j2 = s;
    for (; j2 + 2 <= e; j2 += 2){
      int la = csr[j2];
      int lb = csr[j2+1];
      const int4* ra = (const int4*)&ldsI[la*20 + o2*8];
      const int4* rb = (const int4*)&ldsI[lb*20 + o2*8];
      int4 x0 = ra[0], x1 = ra[1], y0 = rb[0], y1 = rb[1];
      a0 += x0.x + y0.x; a1 += x0.y + y0.y; a2 += x0.z + y0.z; a3 += x0.w + y0.w;
      a4 += x1.x + y1.x; a5 += x1.y + y1.y; a6 += x1.z + y1.z; a7 += x1.w + y1.w;
    }
    if (j2 < e){
      int la = csr[j2];
      const int4* ra = (const int4*)&ldsI[la*20 + o2*8];
      int4 x0 = ra[0], x1 = ra[1];
      a0 += x0.x; a1 += x0.y; a2 += x0.z; a3 += x0.w;
      a4 += x1.x; a5 += x1.y; a6 += x1.z; a7 += x1.w;
    }
    float di = dinv[node] * (1.0f/FXS);
    float mv[8] = {(float)a0*di,(float)a1*di,(float)a2*di,(float)a3*di,
                   (float)a4*di,(float)a5*di,(float)a6*di,(float)a7*di};
    int q = half*2 + o2;
    int base = (((g*64 + (n >> 4))*KC + kc) << 9) + (q*16 + (n & 15))*8;
    ushort hs[8], ls[8];
    #pragma unroll
    for (int ii = 0; ii < 8; ++ii) f2split(mv[ii], hs[ii], ls[ii]);
    *(ushort4*)&Mhi[base]   = make_ushort4(hs[0],hs[1],hs[2],hs[3]);
    *(ushort4*)&Mhi[base+4] = make_ushort4(hs[4],hs[5],hs[6],hs[7]);
    *(ushort4*)&Mlo[base]   = make_ushort4(ls[0],ls[1],ls[2],ls[3]);
    *(ushort4*)&Mlo[base+4] = make_ushort4(ls[4],ls[5],ls[6],ls[7]);
  }
}

// ---------------- GEMM: h = relu(M@Wl + H@Wr + b), fp16x2 dual-accumulator ----------------
// 256 thr = 4 waves. Block = 64 rows x 128 cols. Wave = 2 row-tiles x 4 col-tiles.
// B staged per-kc in 32 KB LDS. NO persistent reg-prefetch (R9 lesson: 64 AGPR acc +
// 32 prefetch VGPRs + frags > 128 under (256,4) -> scratch spills, +180 MB traffic).
// Transient staging regs die before A-frags go live -> peak ~120 regs -> 4 waves/SIMD.
template<int KCI, int MODE>   // MODE0: f16 hi/lo planes out (KC_out=4). MODE1: f16 hi plane + fp32 key (col 127).
__global__ __launch_bounds__(256, 4) void k_gemm(
    const ushort* __restrict__ Ah1, const ushort* __restrict__ Al1,
    const ushort* __restrict__ Ah2, const ushort* __restrict__ Al2,
    const ushort* __restrict__ wlh, const ushort* __restrict__ wll,
    const ushort* __restrict__ wrh, const ushort* __restrict__ wrl,
    const float* __restrict__ bias, ushort* Hho, ushort* Hlo2, float* key){
  __shared__ ushort smB[4*8*512];                // 32 KB: [region(4)][ct(8)][lane(64)][8]
  int t = threadIdx.x, w = t >> 6, l = t & 63;
  int q = l >> 4, m = l & 15;
  int rtl = (w & 1)*2;                           // local row-tile base (0 or 2)
  int ctb = (w >> 1)*4;                          // col-tile base (0 or 4)
  int t0 = blockIdx.x*4;                         // block = 4 row-tiles (64 rows)
  const ushort* warr[4] = {wlh, wll, wrh, wrl};  // (src,plane) = (0,h),(0,l),(1,h),(1,l)
  v4f acc1[2][4], acc2[2][4];                    // [rr][cc]
  #pragma unroll
  for (int a = 0; a < 2; ++a)
    #pragma unroll
    for (int b = 0; b < 4; ++b){ acc1[a][b] = (v4f){0.f,0.f,0.f,0.f}; acc2[a][b] = (v4f){0.f,0.f,0.f,0.f}; }
  v8s* smv = (v8s*)smB;

  for (int kc = 0; kc < KCI; ++kc){
    // stage B(kc): 2048 v8s chunks, 8 per thread (transient regs only)
    #pragma unroll
    for (int i2 = 0; i2 < 8; ++i2){
      int i = i2*256 + t; int r = i >> 9, e2 = i & 511, ct = e2 >> 6, j = e2 & 63;
      smv[i2*256 + t] = *(const v8s*)(warr[r] + ((ct*KCI + kc) << 9) + j*8);
    }
    __syncthreads();                             // B(kc) visible
    // A fragments for this wave's 2 row-tiles (8 loads, batched)
    v8h a1h[2], a1l[2], a2h[2], a2l[2];
    #pragma unroll
    for (int rr = 0; rr < 2; ++rr){
      int aoff = (((t0 + rtl + rr)*KCI + kc) << 9) + l*8;
      a1h[rr] = as_h(*(const v8s*)(Ah1 + aoff));
      a1l[rr] = as_h(*(const v8s*)(Al1 + aoff));
      a2h[rr] = as_h(*(const v8s*)(Ah2 + aoff));
      a2l[rr] = as_h(*(const v8s*)(Al2 + aoff));
    }
    #pragma unroll
    for (int cc = 0; cc < 4; ++cc){
      int ct = ctb + cc;
      v8h b0h = as_h(smv[(0*8 + ct)*64 + l]);
      v8h b0l = as_h(smv[(1*8 + ct)*64 + l]);
      v8h b1h = as_h(smv[(2*8 + ct)*64 + l]);
      v8h b1l = as_h(smv[(3*8 + ct)*64 + l]);
      #pragma unroll
      for (int rr = 0; rr < 2; ++rr){
        acc1[rr][cc] = __builtin_amdgcn_mfma_f32_16x16x32_f16(a1h[rr], b0h, acc1[rr][cc], 0, 0, 0);
        acc2[rr][cc] = __builtin_amdgcn_mfma_f32_16x16x32_f16(a1l[rr], b0h, acc2[rr][cc], 0, 0, 0);
        acc2[rr][cc] = __builtin_amdgcn_mfma_f32_16x16x32_f16(a1h[rr], b0l, acc2[rr][cc], 0, 0, 0);
        acc1[rr][cc] = __builtin_amdgcn_mfma_f32_16x16x32_f16(a2h[rr], b1h, acc1[rr][cc], 0, 0, 0);
        acc2[rr][cc] = __builtin_amdgcn_mfma_f32_16x16x32_f16(a2l[rr], b1h, acc2[rr][cc], 0, 0, 0);
        acc2[rr][cc] = __builtin_amdgcn_mfma_f32_16x16x32_f16(a2h[rr], b1l, acc2[rr][cc], 0, 0, 0);
      }
    }
    if (kc + 1 < KCI) __syncthreads();           // reads done before next stage overwrites
  }
  // epilogue: row = (t0+rtl+rr)*16 + q*4 + r, col = (ctb+cc)*16 + m; dest frag KC_out = 4
  #pragma unroll
  for (int cc = 0; cc < 4; ++cc){
    int ct_g = ctb + cc;
    float badd = bias[ct_g*16 + m];
    #pragma unroll
    for (int rr = 0; rr < 2; ++rr){
      int T = t0 + rtl + rr;
      #pragma unroll
      for (int r = 0; r < 4; ++r){
        float v = fmaxf(acc1[rr][cc][r] + acc2[rr][cc][r]*INV_LOSCALE + badd, 0.0f);
        int lane2 = ((ct_g & 1)*2 + (m >> 3))*16 + q*4 + r;
        int didx = ((T*4 + (ct_g >> 1)) << 9) + lane2*8 + (m & 7);
        if (MODE == 0){
          ushort hi, lo; f2split(v, hi, lo);
          Hho[didx] = hi; Hlo2[didx] = lo;
        } else {
          Hho[didx] = __half_as_ushort(__float2half(v));
          if (ct_g == 7 && m == 15) key[T*16 + q*4 + r] = v;   // exact fp32 sort key (ch 127)
        }
      }
    }
  }
}

// ---------------- sort-pool: coalesced fp32 key read ----------------
__global__ __launch_bounds__(1024) void k_sortpool(const float* __restrict__ keyv, int* __restrict__ sel){
  int g = blockIdx.x, t = threadIdx.x;
  __shared__ unsigned long long key[N_PER];
  __shared__ unsigned long long wred[16];
  float v = keyv[g*N_PER + t];                   // post-relu, v >= 0 -> bits monotone
  key[t] = (((unsigned long long)__float_as_uint(v)) << 10) | (unsigned long long)(N_PER-1 - t);
  __syncthreads();
  for (int r = 0; r < KSP; ++r){
    unsigned long long k = key[t];
    #pragma unroll
    for (int ofs = 32; ofs > 0; ofs >>= 1){
      unsigned long long o2 = __shfl_down(k, ofs, 64);
      if (o2 > k) k = o2;
    }
    if ((t & 63) == 0) wred[t >> 6] = k;
    __syncthreads();
    if (t == 0){
      unsigned long long mm = wred[0];
      #pragma unroll
      for (int j = 1; j < 16; ++j) if (wred[j] > mm) mm = wred[j];
      int idx = (N_PER-1) - (int)(mm & 1023ULL);
      sel[g*KSP + r] = idx;
      key[idx] = 0ULL;
    }
    __syncthreads();
  }
}

// ---------------- head: H3 read from f16 hi plane (frag layout, KC=4) ----------------
__global__ __launch_bounds__(256) void k_head(const ushort* __restrict__ Hhi, const int* __restrict__ sel,
    const float* __restrict__ cwT, const float* __restrict__ cb,
    const float* __restrict__ l1w, const float* __restrict__ l1b,
    const float* __restrict__ l2w, const float* __restrict__ l2b,
    float* __restrict__ out){
  __shared__ __align__(16) float toplds[KSP*HID];
  __shared__ float ypart[8][832];
  __shared__ __align__(16) float yv[832];
  __shared__ float zv[HID];
  int g = blockIdx.x, t = threadIdx.x;
  for (int e = t; e < KSP*HID; e += 256){
    int tt = e >> 7, c = e & 127;
    int n = g*N_PER + sel[g*KSP + tt];
    int idx = ((n >> 4)*4 + (c >> 5))*512 + (((c & 31) >> 3)*16 + (n & 15))*8 + (c & 7);
    toplds[e] = __half2float(__ushort_as_half(Hhi[idx]));
  }
  __syncthreads();
  int o = t & 31, cch = t >> 5;
  float acc[26];
  #pragma unroll
  for (int th = 0; th < 26; ++th) acc[th] = 0.0f;
  for (int c = cch*16; c < cch*16 + 16; ++c){
    float tcol[KSP];
    #pragma unroll
    for (int tt = 0; tt < KSP; ++tt) tcol[tt] = toplds[tt*HID + c];
    float w5[5];
    #pragma unroll
    for (int s = 0; s < 5; ++s) w5[s] = cwT[(c*5 + s)*32 + o];
    #pragma unroll
    for (int th = 0; th < 26; ++th){
      float a2 = acc[th];
      #pragma unroll
      for (int s = 0; s < 5; ++s) a2 += tcol[th + s]*w5[s];
      acc[th] = a2;
    }
  }
  #pragma unroll
  for (int th = 0; th < 26; ++th) ypart[cch][o*26 + th] = acc[th];
  __syncthreads();
  for (int idx = t; idx < 832; idx += 256){
    float s2 = 0.0f;
    #pragma unroll
    for (int j = 0; j < 8; ++j) s2 += ypart[j][idx];
    yv[idx] = fmaxf(s2 + cb[idx / 26], 0.0f);
  }
  __syncthreads();
  if (t < HID){
    float a3 = l1b[t];
    const float4* wr4 = (const float4*)&l1w[t*832];
    const float4* yr4 = (const float4*)yv;
    #pragma unroll 4
    for (int k = 0; k < 208; ++k){
      float4 wv = wr4[k]; float4 yq = yr4[k];
      a3 += wv.x*yq.x + wv.y*yq.y + wv.z*yq.z + wv.w*yq.w;
    }
    zv[t] = fmaxf(a3, 0.0f);
  }
  __syncthreads();
  if (t < OUT_DIM){
    float a4 = l2b[t];
    for (int j = 0; j < HID; ++j) a4 += zv[j]*l2w[t*HID + j];
    out[g*OUT_DIM + t] = a4;
  }
}

extern "C" void kernel_launch(void* const* d_in, const int* in_sizes, int n_in,
                              void* d_out, int out_size, void* d_ws, size_t ws_size,
                              hipStream_t stream){
  const float* x   = (const float*)d_in[0];
  const int*   ei  = (const int*)d_in[1];
  const float* wl1 = (const float*)d_in[3];
  const float* b1  = (const float*)d_in[4];
  const float* wr1 = (const float*)d_in[5];
  const float* wl2 = (const float*)d_in[6];
  const float* b2  = (const float*)d_in[7];
  const float* wr2 = (const float*)d_in[8];
  const float* wl3 = (const float*)d_in[9];
  const float* b3  = (const float*)d_in[10];
  const float* wr3 = (const float*)d_in[11];
  const float* cw  = (const float*)d_in[12];
  const float* cb  = (const float*)d_in[13];
  const float* l1w = (const float*)d_in[14];
  const float* l1b = (const float*)d_in[15];
  const float* l2w = (const float*)d_in[16];
  const float* l2b = (const float*)d_in[17];
  float* out = (float*)d_out;
  const int* esrc = ei;
  const int* edst = ei + N_EDGES;

  char* p = (char*)d_ws;
  auto alloc = [&](size_t bytes)->char*{ char* r = p; p += (bytes + 255) & ~(size_t)255; return r; };
  int*    row_ptr = (int*)alloc((size_t)(N_NODES+1)*4);
  float*  dinv    = (float*)alloc((size_t)N_NODES*4);
  ushort* csr     = (ushort*)alloc((size_t)N_EDGES*2);
  int*    sel     = (int*)alloc((size_t)NGRAPH*KSP*4);
  float*  cwT     = (float*)alloc((size_t)32*HID*5*4);
  float*  keyv    = (float*)alloc((size_t)N_NODES*4);
  ushort* Xhi     = (ushort*)alloc((size_t)N_NODES*32*2);   // 8.4 MB
  ushort* Xlo     = (ushort*)alloc((size_t)N_NODES*32*2);
  ushort* Mhi     = (ushort*)alloc((size_t)N_NODES*HID*2);  // 33.5 MB
  ushort* Mlo     = (ushort*)alloc((size_t)N_NODES*HID*2);
  ushort* Hhi     = (ushort*)alloc((size_t)N_NODES*HID*2);
  ushort* Hlo     = (ushort*)alloc((size_t)N_NODES*HID*2);
  ushort* w1lh = (ushort*)alloc(512*8*2);  ushort* w1ll = (ushort*)alloc(512*8*2);
  ushort* w1rh = (ushort*)alloc(512*8*2);  ushort* w1rl = (ushort*)alloc(512*8*2);
  ushort* w2lh = (ushort*)alloc(512*32*2); ushort* w2ll = (ushort*)alloc(512*32*2);
  ushort* w2rh = (ushort*)alloc(512*32*2); ushort* w2rl = (ushort*)alloc(512*32*2);
  ushort* w3lh = (ushort*)alloc(512*32*2); ushort* w3ll = (ushort*)alloc(512*32*2);
  ushort* w3rh = (ushort*)alloc(512*32*2); ushort* w3rl = (ushort*)alloc(512*32*2);

  k_csr<<<NGRAPH, 1024, 0, stream>>>(esrc, edst, csr, row_ptr, dinv);

  k_pack_x<<<(N_NODES*32)/256, 256, 0, stream>>>(x, Xhi, Xlo);
  k_pack_w<<<(256*32)/256, 256, 0, stream>>>(wl1, wr1, w1lh, w1ll, w1rh, w1rl, 1, IN_CH);
  k_pack_w<<<(256*128)/256, 256, 0, stream>>>(wl2, wr2, w2lh, w2ll, w2rh, w2rl, 4, 128);
  k_pack_w<<<(256*128)/256, 256, 0, stream>>>(wl3, wr3, w3lh, w3ll, w3rh, w3rl, 4, 128);
  k_transpose_cw<<<(32*HID*5 + 255)/256, 256, 0, stream>>>(cw, cwT);

  const int GB = N_NODES/64;       // 2048 gemm blocks (4 row-tiles each)

  // layer 1: M1 = mean(x_nb); h1 = relu(M1@Wl1 + x@Wr1 + b1)  (K padded to 32)
  k_gather<<<NGRAPH*2, 1024, 0, stream>>>(Xhi, Xlo, Mhi, Mlo, row_ptr, csr, dinv, 1);
  k_gemm<1,0><<<GB, 256, 0, stream>>>(Mhi, Mlo, Xhi, Xlo,
      w1lh, w1ll, w1rh, w1rl, b1, Hhi, Hlo, nullptr);
  // layer 2 (in-place h: block reads only its own rows as A before its epilogue writes)
  k_gather<<<NGRAPH*8, 1024, 0, stream>>>(Hhi, Hlo, Mhi, Mlo, row_ptr, csr, dinv, 4);
  k_gemm<4,0><<<GB, 256, 0, stream>>>(Mhi, Mlo, Hhi, Hlo,
      w2lh, w2ll, w2rh, w2rl, b2, Hhi, Hlo, nullptr);
  // layer 3 -> f16 hi plane (head input) + exact fp32 sort key (channel 127)
  k_gather<<<NGRAPH*8, 1024, 0, stream>>>(Hhi, Hlo, Mhi, Mlo, row_ptr, csr, dinv, 4);
  k_gemm<4,1><<<GB, 256, 0, stream>>>(Mhi, Mlo, Hhi, Hlo,
      w3lh, w3ll, w3rh, w3rl, b3, Hhi, nullptr, keyv);

  k_sortpool<<<NGRAPH, 1024, 0, stream>>>(keyv, sel);
  k_head<<<NGRAPH, 256, 0, stream>>>(Hhi, sel, cwT, cb, l1w, l1b, l2w, l2b, out);
}

// Round 11
// 435.843 us; speedup vs baseline: 1.0520x; 1.0453x over previous
//
#include <hip/hip_runtime.h>
#include <hip/hip_bf16.h>
#include <hip/hip_fp16.h>

#define N_NODES 131072
#define N_PER   1024
#define NGRAPH  128
#define N_EDGES 2097152
#define EPG     16384     // edges per graph
#define KSP     30
#define HID     128
#define IN_CH   14
#define OUT_DIM 4

typedef __attribute__((ext_vector_type(8))) short    v8s;
typedef __attribute__((ext_vector_type(8))) _Float16 v8h;
typedef __attribute__((ext_vector_type(4))) float    v4f;

__device__ inline v8h as_h(v8s s){ union { v8s s; v8h h; } u; u.s = s; return u.h; }

// fp32 -> f16 hi + f16 lo (lo pre-scaled by 2^12). hi never denormal.
#define LOSCALE 4096.0f
#define INV_LOSCALE (1.0f/4096.0f)
__device__ inline void f2split(float v, ushort& hi, ushort& lo){
  float av = fabsf(v);
  __half h = (av < 6.103515625e-05f) ? __ushort_as_half((ushort)0) : __float2half(v);
  hi = __half_as_ushort(h);
  lo = __half_as_ushort(__float2half((v - __half2float(h)) * LOSCALE));
}
__device__ inline float f2join(ushort hi, ushort lo){
  return __half2float(__ushort_as_half(hi)) + __half2float(__ushort_as_half(lo)) * INV_LOSCALE;
}

// ---------------- fused per-graph CSR build (count+scan+scatter in LDS) ----------------
__global__ __launch_bounds__(1024) void k_csr(const int* __restrict__ src, const int* __restrict__ dst,
    ushort* __restrict__ csr, int* __restrict__ row_ptr, float* __restrict__ dinv){
  __shared__ ushort lcsr[EPG];     // 32 KB
  __shared__ int ldeg[N_PER];
  __shared__ int lrp[N_PER];
  __shared__ int lcur[N_PER];
  int g = blockIdx.x, t = threadIdx.x;
  int base = g*EPG;
  ldeg[t] = 0;
  __syncthreads();
  #pragma unroll
  for (int r = 0; r < EPG/1024; ++r)
    atomicAdd(&ldeg[dst[base + r*1024 + t] & (N_PER-1)], 1);
  __syncthreads();
  int d = ldeg[t];
  lrp[t] = d;
  __syncthreads();
  for (int ofs = 1; ofs < N_PER; ofs <<= 1){
    int v = lrp[t];
    int add = (t >= ofs) ? lrp[t-ofs] : 0;
    __syncthreads();
    lrp[t] = v + add;
    __syncthreads();
  }
  int ex = lrp[t] - d;               // exclusive prefix
  lcur[t] = ex;
  row_ptr[g*N_PER + t] = base + ex;
  dinv[g*N_PER + t] = d > 0 ? 1.0f/(float)d : 0.0f;
  if (g == NGRAPH-1 && t == 0) row_ptr[N_NODES] = N_EDGES;
  __syncthreads();
  #pragma unroll
  for (int r = 0; r < EPG/1024; ++r){
    int e = base + r*1024 + t;
    int dl = dst[e] & (N_PER-1);
    int pos = atomicAdd(&lcur[dl], 1);
    lcsr[pos] = (ushort)(src[e] & (N_PER-1));
  }
  __syncthreads();
  uint* gout = (uint*)(csr + base);
  const uint* lin = (const uint*)lcsr;
  #pragma unroll
  for (int r = 0; r < EPG/2048; ++r)
    gout[r*1024 + t] = lin[r*1024 + t];
}

// ---------------- prep: pack x / W into MFMA-fragment layouts (f16 hi/lo planes) ----------------
__global__ __launch_bounds__(256) void k_pack_x(const float* __restrict__ x,
                                                ushort* __restrict__ xhi, ushort* __restrict__ xlo){
  int i = blockIdx.x*256 + threadIdx.x;          // N_NODES*32
  int n = i >> 5, k = i & 31;
  float v = (k < IN_CH) ? x[n*IN_CH + k] : 0.0f;
  int dst = (n >> 4)*512 + ((k >> 3)*16 + (n & 15))*8 + (k & 7);
  ushort hi, lo; f2split(v, hi, lo);
  xhi[dst] = hi; xlo[dst] = lo;
}

__global__ __launch_bounds__(256) void k_pack_w(const float* __restrict__ wl, const float* __restrict__ wr,
    ushort* __restrict__ wlh, ushort* __restrict__ wll,
    ushort* __restrict__ wrh, ushort* __restrict__ wrl, int KC, int kin){
  int i = blockIdx.x*256 + threadIdx.x;
  int Kp = KC*32;
  if (i >= 256*Kp) return;
  int which = i / (128*Kp);
  int r = (i / Kp) & 127;
  int k = i % Kp;
  const float* w = which ? wr : wl;
  float v = (k < kin) ? w[r*kin + k] : 0.0f;
  ushort hi, lo; f2split(v, hi, lo);
  int dst = ((r >> 4)*KC + (k >> 5))*512 + ((((k & 31) >> 3))*16 + (r & 15))*8 + (k & 7);
  if (which){ wrh[dst] = hi; wrl[dst] = lo; }
  else      { wlh[dst] = hi; wll[dst] = lo; }
}

__global__ __launch_bounds__(256) void k_transpose_cw(const float* __restrict__ cw, float* __restrict__ cwT){
  int e = blockIdx.x*256 + threadIdx.x;          // 32*128*5
  if (e < 32*HID*5){
    int o = e / 640, rem = e % 640;
    cwT[rem*32 + o] = cw[e];
  }
}

// ---------------- gather: M[i] = mean_{j->i} H[j] (frag layout in/out) ----------------
#define FXS 262144.0f
__global__ __launch_bounds__(1024) void k_gather(
    const ushort* __restrict__ Hhi, const ushort* __restrict__ Hlo,
    ushort* __restrict__ Mhi, ushort* __restrict__ Mlo,
    const int* __restrict__ row_ptr, const ushort* __restrict__ csr,
    const float* __restrict__ dinv, int KC){
  __shared__ int ldsI[N_PER*20];                 // 80 KB
  int P = KC*2;
  int g = blockIdx.x / P, p = blockIdx.x % P;
  int kc = p >> 1, half = p & 1;
  int t = threadIdx.x;
  for (int it = t; it < 16384; it += 1024){
    int Tl = it >> 8, e = it & 255;
    int idx = (((g*64 + Tl)*KC + kc) << 9) + (half << 8) + e;
    float v = f2join(Hhi[idx], Hlo[idx]);
    int l = e >> 3, j = e & 7;
    int m = l & 15, qh = l >> 4;
    ldsI[(Tl*16 + m)*20 + qh*8 + j] = __float2int_rn(v*FXS);
  }
  __syncthreads();
  int o2 = t & 1, ns = t >> 1;
  #pragma unroll
  for (int rep = 0; rep < 2; ++rep){
    int n = ns + rep*512;
    int node = g*N_PER + n;
    int s = row_ptr[node], e = row_ptr[node+1];
    int a0=0,a1=0,a2=0,a3=0,a4=0,a5=0,a6=0,a7=0;
    int j2 = s;
    for (; j2 + 2 <= e; j2 += 2){
      int la = csr[j2];
      int lb = csr[j2+1];
      const int4* ra = (const int4*)&ldsI[la*20 + o2*8];
      const int4* rb = (const int4*)&ldsI[lb*20 + o2*8];
      int4 x0 = ra[0], x1 = ra[1], y0 = rb[0], y1 = rb[1];
      a0 += x0.x + y0.x; a1 += x0.y + y0.y; a2 += x0.z + y0.z; a3 += x0.w + y0.w;
      a4 += x1.x + y1.x; a5 += x1.y + y1.y; a6 += x1.z + y1.z; a7 += x1.w + y1.w;
    }
    if (j2 < e){
      int la = csr[j2];
      const int4* ra = (const int4*)&ldsI[la*20 + o2*8];
      int4 x0 = ra[0], x1 = ra[1];
      a0 += x0.x; a1 += x0.y; a2 += x0.z; a3 += x0.w;
      a4 += x1.x; a5 += x1.y; a6 += x1.z; a7 += x1.w;
    }
    float di = dinv[node] * (1.0f/FXS);
    float mv[8] = {(float)a0*di,(float)a1*di,(float)a2*di,(float)a3*di,
                   (float)a4*di,(float)a5*di,(float)a6*di,(float)a7*di};
    int q = half*2 + o2;
    int base = (((g*64 + (n >> 4))*KC + kc) << 9) + (q*16 + (n & 15))*8;
    ushort hs[8], ls[8];
    #pragma unroll
    for (int ii = 0; ii < 8; ++ii) f2split(mv[ii], hs[ii], ls[ii]);
    *(ushort4*)&Mhi[base]   = make_ushort4(hs[0],hs[1],hs[2],hs[3]);
    *(ushort4*)&Mhi[base+4] = make_ushort4(hs[4],hs[5],hs[6],hs[7]);
    *(ushort4*)&Mlo[base]   = make_ushort4(ls[0],ls[1],ls[2],ls[3]);
    *(ushort4*)&Mlo[base+4] = make_ushort4(ls[4],ls[5],ls[6],ls[7]);
  }
}

// ---------------- GEMM: h = relu(M@Wl + H@Wr + b), fp16x2 dual-accumulator ----------------
// 256 thr = 4 waves. Block = 64 rows x 128 cols. Wave = 2 row-tiles x 4 col-tiles.
// B staged per-kc in 32 KB LDS (two 4-chunk batches -> 16-reg transient).
// src-OUTER loop (M pass then H pass per kc) reuses one 16-reg A-frag set — R10's
// both-src-live version peaked ~135 regs under the (256,4) 128-reg cap -> scratch
// spills (FETCH 86/WRITE 100 MB vs 67/65.5 ideal). Peak now ~105 regs, no spill.
template<int KCI, int MODE>   // MODE0: f16 hi/lo planes out (KC_out=4). MODE1: f16 hi plane + fp32 key (col 127).
__global__ __launch_bounds__(256, 4) void k_gemm(
    const ushort* __restrict__ Ah1, const ushort* __restrict__ Al1,
    const ushort* __restrict__ Ah2, const ushort* __restrict__ Al2,
    const ushort* __restrict__ wlh, const ushort* __restrict__ wll,
    const ushort* __restrict__ wrh, const ushort* __restrict__ wrl,
    const float* __restrict__ bias, ushort* Hho, ushort* Hlo2, float* key){
  __shared__ ushort smB[4*8*512];                // 32 KB: [region(4)][ct(8)][lane(64)][8]
  int t = threadIdx.x, w = t >> 6, l = t & 63;
  int q = l >> 4, m = l & 15;
  int rtl = (w & 1)*2;                           // local row-tile base (0 or 2)
  int ctb = (w >> 1)*4;                          // col-tile base (0 or 4)
  int t0 = blockIdx.x*4;                         // block = 4 row-tiles (64 rows)
  const ushort* warr[4] = {wlh, wll, wrh, wrl};  // (src,plane) = (0,h),(0,l),(1,h),(1,l)
  v4f acc1[2][4], acc2[2][4];                    // [rr][cc]
  #pragma unroll
  for (int a = 0; a < 2; ++a)
    #pragma unroll
    for (int b = 0; b < 4; ++b){ acc1[a][b] = (v4f){0.f,0.f,0.f,0.f}; acc2[a][b] = (v4f){0.f,0.f,0.f,0.f}; }
  v8s* smv = (v8s*)smB;

  for (int kc = 0; kc < KCI; ++kc){
    // stage B(kc): 2048 v8s chunks in two 4-chunk batches (16-reg transient)
    #pragma unroll
    for (int h2 = 0; h2 < 2; ++h2){
      v8s st[4];
      #pragma unroll
      for (int i2 = 0; i2 < 4; ++i2){
        int i = (h2*4 + i2)*256 + t; int r = i >> 9, e2 = i & 511, ct = e2 >> 6, j = e2 & 63;
        st[i2] = *(const v8s*)(warr[r] + ((ct*KCI + kc) << 9) + j*8);
      }
      #pragma unroll
      for (int i2 = 0; i2 < 4; ++i2) smv[(h2*4 + i2)*256 + t] = st[i2];
    }
    __syncthreads();                             // B(kc) visible
    #pragma unroll
    for (int src = 0; src < 2; ++src){
      const ushort* AH = src ? Ah2 : Ah1;
      const ushort* AL = src ? Al2 : Al1;
      v8h ah[2], al[2];
      #pragma unroll
      for (int rr = 0; rr < 2; ++rr){
        int aoff = (((t0 + rtl + rr)*KCI + kc) << 9) + l*8;
        ah[rr] = as_h(*(const v8s*)(AH + aoff));
        al[rr] = as_h(*(const v8s*)(AL + aoff));
      }
      #pragma unroll
      for (int cc = 0; cc < 4; ++cc){
        int ct = ctb + cc;
        v8h bh = as_h(smv[((src*2 + 0)*8 + ct)*64 + l]);
        v8h bl = as_h(smv[((src*2 + 1)*8 + ct)*64 + l]);
        #pragma unroll
        for (int rr = 0; rr < 2; ++rr){
          acc1[rr][cc] = __builtin_amdgcn_mfma_f32_16x16x32_f16(ah[rr], bh, acc1[rr][cc], 0, 0, 0);
          acc2[rr][cc] = __builtin_amdgcn_mfma_f32_16x16x32_f16(al[rr], bh, acc2[rr][cc], 0, 0, 0);
          acc2[rr][cc] = __builtin_amdgcn_mfma_f32_16x16x32_f16(ah[rr], bl, acc2[rr][cc], 0, 0, 0);
        }
      }
    }
    if (kc + 1 < KCI) __syncthreads();           // reads done before next stage overwrites
  }
  // epilogue: row = (t0+rtl+rr)*16 + q*4 + r, col = (ctb+cc)*16 + m; dest frag KC_out = 4
  #pragma unroll
  for (int cc = 0; cc < 4; ++cc){
    int ct_g = ctb + cc;
    float badd = bias[ct_g*16 + m];
    #pragma unroll
    for (int rr = 0; rr < 2; ++rr){
      int T = t0 + rtl + rr;
      #pragma unroll
      for (int r = 0; r < 4; ++r){
        float v = fmaxf(acc1[rr][cc][r] + acc2[rr][cc][r]*INV_LOSCALE + badd, 0.0f);
        int lane2 = ((ct_g & 1)*2 + (m >> 3))*16 + q*4 + r;
        int didx = ((T*4 + (ct_g >> 1)) << 9) + lane2*8 + (m & 7);
        if (MODE == 0){
          ushort hi, lo; f2split(v, hi, lo);
          Hho[didx] = hi; Hlo2[didx] = lo;
        } else {
          Hho[didx] = __half_as_ushort(__float2half(v));
          if (ct_g == 7 && m == 15) key[T*16 + q*4 + r] = v;   // exact fp32 sort key (ch 127)
        }
      }
    }
  }
}

// ---------------- sort-pool: coalesced fp32 key read ----------------
__global__ __launch_bounds__(1024) void k_sortpool(const float* __restrict__ keyv, int* __restrict__ sel){
  int g = blockIdx.x, t = threadIdx.x;
  __shared__ unsigned long long key[N_PER];
  __shared__ unsigned long long wred[16];
  float v = keyv[g*N_PER + t];                   // post-relu, v >= 0 -> bits monotone
  key[t] = (((unsigned long long)__float_as_uint(v)) << 10) | (unsigned long long)(N_PER-1 - t);
  __syncthreads();
  for (int r = 0; r < KSP; ++r){
    unsigned long long k = key[t];
    #pragma unroll
    for (int ofs = 32; ofs > 0; ofs >>= 1){
      unsigned long long o2 = __shfl_down(k, ofs, 64);
      if (o2 > k) k = o2;
    }
    if ((t & 63) == 0) wred[t >> 6] = k;
    __syncthreads();
    if (t == 0){
      unsigned long long mm = wred[0];
      #pragma unroll
      for (int j = 1; j < 16; ++j) if (wred[j] > mm) mm = wred[j];
      int idx = (N_PER-1) - (int)(mm & 1023ULL);
      sel[g*KSP + r] = idx;
      key[idx] = 0ULL;
    }
    __syncthreads();
  }
}

// ---------------- head: H3 read from f16 hi plane (frag layout, KC=4) ----------------
__global__ __launch_bounds__(256) void k_head(const ushort* __restrict__ Hhi, const int* __restrict__ sel,
    const float* __restrict__ cwT, const float* __restrict__ cb,
    const float* __restrict__ l1w, const float* __restrict__ l1b,
    const float* __restrict__ l2w, const float* __restrict__ l2b,
    float* __restrict__ out){
  __shared__ __align__(16) float toplds[KSP*HID];
  __shared__ float ypart[8][832];
  __shared__ __align__(16) float yv[832];
  __shared__ float zv[HID];
  int g = blockIdx.x, t = threadIdx.x;
  for (int e = t; e < KSP*HID; e += 256){
    int tt = e >> 7, c = e & 127;
    int n = g*N_PER + sel[g*KSP + tt];
    int idx = ((n >> 4)*4 + (c >> 5))*512 + (((c & 31) >> 3)*16 + (n & 15))*8 + (c & 7);
    toplds[e] = __half2float(__ushort_as_half(Hhi[idx]));
  }
  __syncthreads();
  int o = t & 31, cch = t >> 5;
  float acc[26];
  #pragma unroll
  for (int th = 0; th < 26; ++th) acc[th] = 0.0f;
  for (int c = cch*16; c < cch*16 + 16; ++c){
    float tcol[KSP];
    #pragma unroll
    for (int tt = 0; tt < KSP; ++tt) tcol[tt] = toplds[tt*HID + c];
    float w5[5];
    #pragma unroll
    for (int s = 0; s < 5; ++s) w5[s] = cwT[(c*5 + s)*32 + o];
    #pragma unroll
    for (int th = 0; th < 26; ++th){
      float a2 = acc[th];
      #pragma unroll
      for (int s = 0; s < 5; ++s) a2 += tcol[th + s]*w5[s];
      acc[th] = a2;
    }
  }
  #pragma unroll
  for (int th = 0; th < 26; ++th) ypart[cch][o*26 + th] = acc[th];
  __syncthreads();
  for (int idx = t; idx < 832; idx += 256){
    float s2 = 0.0f;
    #pragma unroll
    for (int j = 0; j < 8; ++j) s2 += ypart[j][idx];
    yv[idx] = fmaxf(s2 + cb[idx / 26], 0.0f);
  }
  __syncthreads();
  if (t < HID){
    float a3 = l1b[t];
    const float4* wr4 = (const float4*)&l1w[t*832];
    const float4* yr4 = (const float4*)yv;
    #pragma unroll 4
    for (int k = 0; k < 208; ++k){
      float4 wv = wr4[k]; float4 yq = yr4[k];
      a3 += wv.x*yq.x + wv.y*yq.y + wv.z*yq.z + wv.w*yq.w;
    }
    zv[t] = fmaxf(a3, 0.0f);
  }
  __syncthreads();
  if (t < OUT_DIM){
    float a4 = l2b[t];
    for (int j = 0; j < HID; ++j) a4 += zv[j]*l2w[t*HID + j];
    out[g*OUT_DIM + t] = a4;
  }
}

extern "C" void kernel_launch(void* const* d_in, const int* in_sizes, int n_in,
                              void* d_out, int out_size, void* d_ws, size_t ws_size,
                              hipStream_t stream){
  const float* x   = (const float*)d_in[0];
  const int*   ei  = (const int*)d_in[1];
  const float* wl1 = (const float*)d_in[3];
  const float* b1  = (const float*)d_in[4];
  const float* wr1 = (const float*)d_in[5];
  const float* wl2 = (const float*)d_in[6];
  const float* b2  = (const float*)d_in[7];
  const float* wr2 = (const float*)d_in[8];
  const float* wl3 = (const float*)d_in[9];
  const float* b3  = (const float*)d_in[10];
  const float* wr3 = (const float*)d_in[11];
  const float* cw  = (const float*)d_in[12];
  const float* cb  = (const float*)d_in[13];
  const float* l1w = (const float*)d_in[14];
  const float* l1b = (const float*)d_in[15];
  const float* l2w = (const float*)d_in[16];
  const float* l2b = (const float*)d_in[17];
  float* out = (float*)d_out;
  const int* esrc = ei;
  const int* edst = ei + N_EDGES;

  char* p = (char*)d_ws;
  auto alloc = [&](size_t bytes)->char*{ char* r = p; p += (bytes + 255) & ~(size_t)255; return r; };
  int*    row_ptr = (int*)alloc((size_t)(N_NODES+1)*4);
  float*  dinv    = (float*)alloc((size_t)N_NODES*4);
  ushort* csr     = (ushort*)alloc((size_t)N_EDGES*2);
  int*    sel     = (int*)alloc((size_t)NGRAPH*KSP*4);
  float*  cwT     = (float*)alloc((size_t)32*HID*5*4);
  float*  keyv    = (float*)alloc((size_t)N_NODES*4);
  ushort* Xhi     = (ushort*)alloc((size_t)N_NODES*32*2);   // 8.4 MB
  ushort* Xlo     = (ushort*)alloc((size_t)N_NODES*32*2);
  ushort* Mhi     = (ushort*)alloc((size_t)N_NODES*HID*2);  // 33.5 MB
  ushort* Mlo     = (ushort*)alloc((size_t)N_NODES*HID*2);
  ushort* Hhi     = (ushort*)alloc((size_t)N_NODES*HID*2);
  ushort* Hlo     = (ushort*)alloc((size_t)N_NODES*HID*2);
  ushort* w1lh = (ushort*)alloc(512*8*2);  ushort* w1ll = (ushort*)alloc(512*8*2);
  ushort* w1rh = (ushort*)alloc(512*8*2);  ushort* w1rl = (ushort*)alloc(512*8*2);
  ushort* w2lh = (ushort*)alloc(512*32*2); ushort* w2ll = (ushort*)alloc(512*32*2);
  ushort* w2rh = (ushort*)alloc(512*32*2); ushort* w2rl = (ushort*)alloc(512*32*2);
  ushort* w3lh = (ushort*)alloc(512*32*2); ushort* w3ll = (ushort*)alloc(512*32*2);
  ushort* w3rh = (ushort*)alloc(512*32*2); ushort* w3rl = (ushort*)alloc(512*32*2);

  k_csr<<<NGRAPH, 1024, 0, stream>>>(esrc, edst, csr, row_ptr, dinv);

  k_pack_x<<<(N_NODES*32)/256, 256, 0, stream>>>(x, Xhi, Xlo);
  k_pack_w<<<(256*32)/256, 256, 0, stream>>>(wl1, wr1, w1lh, w1ll, w1rh, w1rl, 1, IN_CH);
  k_pack_w<<<(256*128)/256, 256, 0, stream>>>(wl2, wr2, w2lh, w2ll, w2rh, w2rl, 4, 128);
  k_pack_w<<<(256*128)/256, 256, 0, stream>>>(wl3, wr3, w3lh, w3ll, w3rh, w3rl, 4, 128);
  k_transpose_cw<<<(32*HID*5 + 255)/256, 256, 0, stream>>>(cw, cwT);

  const int GB = N_NODES/64;       // 2048 gemm blocks (4 row-tiles each)

  // layer 1: M1 = mean(x_nb); h1 = relu(M1@Wl1 + x@Wr1 + b1)  (K padded to 32)
  k_gather<<<NGRAPH*2, 1024, 0, stream>>>(Xhi, Xlo, Mhi, Mlo, row_ptr, csr, dinv, 1);
  k_gemm<1,0><<<GB, 256, 0, stream>>>(Mhi, Mlo, Xhi, Xlo,
      w1lh, w1ll, w1rh, w1rl, b1, Hhi, Hlo, nullptr);
  // layer 2 (in-place h: block reads only its own rows as A before its epilogue writes)
  k_gather<<<NGRAPH*8, 1024, 0, stream>>>(Hhi, Hlo, Mhi, Mlo, row_ptr, csr, dinv, 4);
  k_gemm<4,0><<<GB, 256, 0, stream>>>(Mhi, Mlo, Hhi, Hlo,
      w2lh, w2ll, w2rh, w2rl, b2, Hhi, Hlo, nullptr);
  // layer 3 -> f16 hi plane (head input) + exact fp32 sort key (channel 127)
  k_gather<<<NGRAPH*8, 1024, 0, stream>>>(Hhi, Hlo, Mhi, Mlo, row_ptr, csr, dinv, 4);
  k_gemm<4,1><<<GB, 256, 0, stream>>>(Mhi, Mlo, Hhi, Hlo,
      w3lh, w3ll, w3rh, w3rl, b3, Hhi, nullptr, keyv);

  k_sortpool<<<NGRAPH, 1024, 0, stream>>>(keyv, sel);
  k_head<<<NGRAPH, 256, 0, stream>>>(Hhi, sel, cwT, cb, l1w, l1b, l2w, l2b, out);
}

// Round 12
// 431.026 us; speedup vs baseline: 1.0637x; 1.0112x over previous
//
#include <hip/hip_runtime.h>
#include <hip/hip_bf16.h>
#include <hip/hip_fp16.h>

#define N_NODES 131072
#define N_PER   1024
#define NGRAPH  128
#define N_EDGES 2097152
#define EPG     16384     // edges per graph
#define KSP     30
#define HID     128
#define IN_CH   14
#define OUT_DIM 4

typedef __attribute__((ext_vector_type(8))) short    v8s;
typedef __attribute__((ext_vector_type(8))) _Float16 v8h;
typedef __attribute__((ext_vector_type(4))) float    v4f;

__device__ inline v8h as_h(v8s s){ union { v8s s; v8h h; } u; u.s = s; return u.h; }

// fp32 -> f16 hi + f16 lo (lo pre-scaled by 2^12). hi never denormal.
#define LOSCALE 4096.0f
#define INV_LOSCALE (1.0f/4096.0f)
__device__ inline void f2split(float v, ushort& hi, ushort& lo){
  float av = fabsf(v);
  __half h = (av < 6.103515625e-05f) ? __ushort_as_half((ushort)0) : __float2half(v);
  hi = __half_as_ushort(h);
  lo = __half_as_ushort(__float2half((v - __half2float(h)) * LOSCALE));
}
__device__ inline float f2join(ushort hi, ushort lo){
  return __half2float(__ushort_as_half(hi)) + __half2float(__ushort_as_half(lo)) * INV_LOSCALE;
}

// ---------------- fused per-graph CSR build (count+scan+scatter in LDS) ----------------
__global__ __launch_bounds__(1024) void k_csr(const int* __restrict__ src, const int* __restrict__ dst,
    ushort* __restrict__ csr, int* __restrict__ row_ptr, float* __restrict__ dinv){
  __shared__ ushort lcsr[EPG];     // 32 KB
  __shared__ int ldeg[N_PER];
  __shared__ int lrp[N_PER];
  __shared__ int lcur[N_PER];
  int g = blockIdx.x, t = threadIdx.x;
  int base = g*EPG;
  ldeg[t] = 0;
  __syncthreads();
  #pragma unroll
  for (int r = 0; r < EPG/1024; ++r)
    atomicAdd(&ldeg[dst[base + r*1024 + t] & (N_PER-1)], 1);
  __syncthreads();
  int d = ldeg[t];
  lrp[t] = d;
  __syncthreads();
  for (int ofs = 1; ofs < N_PER; ofs <<= 1){
    int v = lrp[t];
    int add = (t >= ofs) ? lrp[t-ofs] : 0;
    __syncthreads();
    lrp[t] = v + add;
    __syncthreads();
  }
  int ex = lrp[t] - d;               // exclusive prefix
  lcur[t] = ex;
  row_ptr[g*N_PER + t] = base + ex;
  dinv[g*N_PER + t] = d > 0 ? 1.0f/(float)d : 0.0f;
  if (g == NGRAPH-1 && t == 0) row_ptr[N_NODES] = N_EDGES;
  __syncthreads();
  #pragma unroll
  for (int r = 0; r < EPG/1024; ++r){
    int e = base + r*1024 + t;
    int dl = dst[e] & (N_PER-1);
    int pos = atomicAdd(&lcur[dl], 1);
    lcsr[pos] = (ushort)(src[e] & (N_PER-1));
  }
  __syncthreads();
  uint* gout = (uint*)(csr + base);
  const uint* lin = (const uint*)lcsr;
  #pragma unroll
  for (int r = 0; r < EPG/2048; ++r)
    gout[r*1024 + t] = lin[r*1024 + t];
}

// ---------------- prep: pack x / W into MFMA-fragment layouts (f16 hi/lo planes) ----------------
__global__ __launch_bounds__(256) void k_pack_x(const float* __restrict__ x,
                                                ushort* __restrict__ xhi, ushort* __restrict__ xlo){
  int i = blockIdx.x*256 + threadIdx.x;          // N_NODES*32
  int n = i >> 5, k = i & 31;
  float v = (k < IN_CH) ? x[n*IN_CH + k] : 0.0f;
  int dst = (n >> 4)*512 + ((k >> 3)*16 + (n & 15))*8 + (k & 7);
  ushort hi, lo; f2split(v, hi, lo);
  xhi[dst] = hi; xlo[dst] = lo;
}

__global__ __launch_bounds__(256) void k_pack_w(const float* __restrict__ wl, const float* __restrict__ wr,
    ushort* __restrict__ wlh, ushort* __restrict__ wll,
    ushort* __restrict__ wrh, ushort* __restrict__ wrl, int KC, int kin){
  int i = blockIdx.x*256 + threadIdx.x;
  int Kp = KC*32;
  if (i >= 256*Kp) return;
  int which = i / (128*Kp);
  int r = (i / Kp) & 127;
  int k = i % Kp;
  const float* w = which ? wr : wl;
  float v = (k < kin) ? w[r*kin + k] : 0.0f;
  ushort hi, lo; f2split(v, hi, lo);
  int dst = ((r >> 4)*KC + (k >> 5))*512 + ((((k & 31) >> 3))*16 + (r & 15))*8 + (k & 7);
  if (which){ wrh[dst] = hi; wrl[dst] = lo; }
  else      { wlh[dst] = hi; wll[dst] = lo; }
}

__global__ __launch_bounds__(256) void k_transpose_cw(const float* __restrict__ cw, float* __restrict__ cwT){
  int e = blockIdx.x*256 + threadIdx.x;          // 32*128*5
  if (e < 32*HID*5){
    int o = e / 640, rem = e % 640;
    cwT[rem*32 + o] = cw[e];
  }
}

// ---------------- gather: M[i] = mean_{j->i} H[j] (frag layout in/out) ----------------
// 4-edge unrolled inner loop: 4 independent csr loads + 8 ds_read_b128 per iter
// (was 2 -> serial global csr latency gated the loop).
#define FXS 262144.0f
__global__ __launch_bounds__(1024) void k_gather(
    const ushort* __restrict__ Hhi, const ushort* __restrict__ Hlo,
    ushort* __restrict__ Mhi, ushort* __restrict__ Mlo,
    const int* __restrict__ row_ptr, const ushort* __restrict__ csr,
    const float* __restrict__ dinv, int KC){
  __shared__ int ldsI[N_PER*20];                 // 80 KB
  int P = KC*2;
  int g = blockIdx.x / P, p = blockIdx.x % P;
  int kc = p >> 1, half = p & 1;
  int t = threadIdx.x;
  for (int it = t; it < 16384; it += 1024){
    int Tl = it >> 8, e = it & 255;
    int idx = (((g*64 + Tl)*KC + kc) << 9) + (half << 8) + e;
    float v = f2join(Hhi[idx], Hlo[idx]);
    int l = e >> 3, j = e & 7;
    int m = l & 15, qh = l >> 4;
    ldsI[(Tl*16 + m)*20 + qh*8 + j] = __float2int_rn(v*FXS);
  }
  __syncthreads();
  int o2 = t & 1, ns = t >> 1;
  #pragma unroll
  for (int rep = 0; rep < 2; ++rep){
    int n = ns + rep*512;
    int node = g*N_PER + n;
    int s = row_ptr[node], e = row_ptr[node+1];
    int a0=0,a1=0,a2=0,a3=0,a4=0,a5=0,a6=0,a7=0;
    int j2 = s;
    for (; j2 + 4 <= e; j2 += 4){
      int la = csr[j2], lb = csr[j2+1], lc = csr[j2+2], ld = csr[j2+3];
      const int4* ra = (const int4*)&ldsI[la*20 + o2*8];
      const int4* rb = (const int4*)&ldsI[lb*20 + o2*8];
      const int4* rc = (const int4*)&ldsI[lc*20 + o2*8];
      const int4* rd = (const int4*)&ldsI[ld*20 + o2*8];
      int4 x0 = ra[0], x1 = ra[1], y0 = rb[0], y1 = rb[1];
      int4 z0 = rc[0], z1 = rc[1], u0 = rd[0], u1 = rd[1];
      a0 += (x0.x + y0.x) + (z0.x + u0.x);
      a1 += (x0.y + y0.y) + (z0.y + u0.y);
      a2 += (x0.z + y0.z) + (z0.z + u0.z);
      a3 += (x0.w + y0.w) + (z0.w + u0.w);
      a4 += (x1.x + y1.x) + (z1.x + u1.x);
      a5 += (x1.y + y1.y) + (z1.y + u1.y);
      a6 += (x1.z + y1.z) + (z1.z + u1.z);
      a7 += (x1.w + y1.w) + (z1.w + u1.w);
    }
    for (; j2 < e; ++j2){
      int la = csr[j2];
      const int4* ra = (const int4*)&ldsI[la*20 + o2*8];
      int4 x0 = ra[0], x1 = ra[1];
      a0 += x0.x; a1 += x0.y; a2 += x0.z; a3 += x0.w;
      a4 += x1.x; a5 += x1.y; a6 += x1.z; a7 += x1.w;
    }
    float di = dinv[node] * (1.0f/FXS);
    float mv[8] = {(float)a0*di,(float)a1*di,(float)a2*di,(float)a3*di,
                   (float)a4*di,(float)a5*di,(float)a6*di,(float)a7*di};
    int q = half*2 + o2;
    int base = (((g*64 + (n >> 4))*KC + kc) << 9) + (q*16 + (n & 15))*8;
    ushort hs[8], ls[8];
    #pragma unroll
    for (int ii = 0; ii < 8; ++ii) f2split(mv[ii], hs[ii], ls[ii]);
    *(ushort4*)&Mhi[base]   = make_ushort4(hs[0],hs[1],hs[2],hs[3]);
    *(ushort4*)&Mhi[base+4] = make_ushort4(hs[4],hs[5],hs[6],hs[7]);
    *(ushort4*)&Mlo[base]   = make_ushort4(ls[0],ls[1],ls[2],ls[3]);
    *(ushort4*)&Mlo[base+4] = make_ushort4(ls[4],ls[5],ls[6],ls[7]);
  }
}

// ---------------- GEMM: h = relu(M@Wl + H@Wr + b), fp16x2 dual-accumulator ----------------
// R8 config restored verbatim — best measured (54.4 us, no spill): 2rt x 4ct wave tile,
// persistent B reg-prefetch pipeline, (256,2). Lesson from R9-R11: with 64 acc regs the
// 128-reg cap of (256,4) is unreachable without scratch spills (FETCH/WRITE inflation);
// 144 total regs at 2 blocks/CU beats spilling at nominal 4 blocks/CU.
template<int KCI, int MODE>   // MODE0: f16 hi/lo planes out (KC_out=4). MODE1: f16 hi plane + fp32 key (col 127).
__global__ __launch_bounds__(256, 2) void k_gemm(
    const ushort* __restrict__ Ah1, const ushort* __restrict__ Al1,
    const ushort* __restrict__ Ah2, const ushort* __restrict__ Al2,
    const ushort* __restrict__ wlh, const ushort* __restrict__ wll,
    const ushort* __restrict__ wrh, const ushort* __restrict__ wrl,
    const float* __restrict__ bias, ushort* Hho, ushort* Hlo2, float* key){
  __shared__ ushort smB[4*8*512];                // 32 KB: [region(4)][ct(8)][lane(64)][8]
  int t = threadIdx.x, w = t >> 6, l = t & 63;
  int q = l >> 4, m = l & 15;
  int rtl = (w & 1)*2;                           // local row-tile base (0 or 2)
  int ctb = (w >> 1)*4;                          // col-tile base (0 or 4)
  int t0 = blockIdx.x*4;                         // block = 4 row-tiles (64 rows)
  const ushort* warr[4] = {wlh, wll, wrh, wrl};  // (src,plane) = (0,h),(0,l),(1,h),(1,l)
  v4f acc1[2][4], acc2[2][4];                    // [rr][cc]
  #pragma unroll
  for (int a = 0; a < 2; ++a)
    #pragma unroll
    for (int b = 0; b < 4; ++b){ acc1[a][b] = (v4f){0.f,0.f,0.f,0.f}; acc2[a][b] = (v4f){0.f,0.f,0.f,0.f}; }
  v8s* smv = (v8s*)smB;
  v8s pre[8];
  // prefetch B(kc=0) and commit
  #pragma unroll
  for (int i2 = 0; i2 < 8; ++i2){
    int i = i2*256 + t; int r = i >> 9, e2 = i & 511, ct = e2 >> 6, j = e2 & 63;
    pre[i2] = *(const v8s*)(warr[r] + ((ct*KCI + 0) << 9) + j*8);
  }
  #pragma unroll
  for (int i2 = 0; i2 < 8; ++i2) smv[i2*256 + t] = pre[i2];

  for (int kc = 0; kc < KCI; ++kc){
    __syncthreads();                             // B(kc) visible in LDS
    if (kc + 1 < KCI){
      #pragma unroll
      for (int i2 = 0; i2 < 8; ++i2){
        int i = i2*256 + t; int r = i >> 9, e2 = i & 511, ct = e2 >> 6, j = e2 & 63;
        pre[i2] = *(const v8s*)(warr[r] + ((ct*KCI + kc + 1) << 9) + j*8);
      }
    }
    // A fragments for this wave's 2 row-tiles (8 loads, batched)
    v8h a1h[2], a1l[2], a2h[2], a2l[2];
    #pragma unroll
    for (int rr = 0; rr < 2; ++rr){
      int aoff = (((t0 + rtl + rr)*KCI + kc) << 9) + l*8;
      a1h[rr] = as_h(*(const v8s*)(Ah1 + aoff));
      a1l[rr] = as_h(*(const v8s*)(Al1 + aoff));
      a2h[rr] = as_h(*(const v8s*)(Ah2 + aoff));
      a2l[rr] = as_h(*(const v8s*)(Al2 + aoff));
    }
    #pragma unroll
    for (int cc = 0; cc < 4; ++cc){
      int ct = ctb + cc;
      v8h b0h = as_h(smv[(0*8 + ct)*64 + l]);
      v8h b0l = as_h(smv[(1*8 + ct)*64 + l]);
      v8h b1h = as_h(smv[(2*8 + ct)*64 + l]);
      v8h b1l = as_h(smv[(3*8 + ct)*64 + l]);
      #pragma unroll
      for (int rr = 0; rr < 2; ++rr){
        acc1[rr][cc] = __builtin_amdgcn_mfma_f32_16x16x32_f16(a1h[rr], b0h, acc1[rr][cc], 0, 0, 0);
        acc2[rr][cc] = __builtin_amdgcn_mfma_f32_16x16x32_f16(a1l[rr], b0h, acc2[rr][cc], 0, 0, 0);
        acc2[rr][cc] = __builtin_amdgcn_mfma_f32_16x16x32_f16(a1h[rr], b0l, acc2[rr][cc], 0, 0, 0);
        acc1[rr][cc] = __builtin_amdgcn_mfma_f32_16x16x32_f16(a2h[rr], b1h, acc1[rr][cc], 0, 0, 0);
        acc2[rr][cc] = __builtin_amdgcn_mfma_f32_16x16x32_f16(a2l[rr], b1h, acc2[rr][cc], 0, 0, 0);
        acc2[rr][cc] = __builtin_amdgcn_mfma_f32_16x16x32_f16(a2h[rr], b1l, acc2[rr][cc], 0, 0, 0);
      }
    }
    __syncthreads();                             // all waves done reading B(kc)
    if (kc + 1 < KCI){
      #pragma unroll
      for (int i2 = 0; i2 < 8; ++i2) smv[i2*256 + t] = pre[i2];
    }
  }
  // epilogue: row = (t0+rtl+rr)*16 + q*4 + r, col = (ctb+cc)*16 + m; dest frag KC_out = 4
  #pragma unroll
  for (int cc = 0; cc < 4; ++cc){
    int ct_g = ctb + cc;
    float badd = bias[ct_g*16 + m];
    #pragma unroll
    for (int rr = 0; rr < 2; ++rr){
      int T = t0 + rtl + rr;
      #pragma unroll
      for (int r = 0; r < 4; ++r){
        float v = fmaxf(acc1[rr][cc][r] + acc2[rr][cc][r]*INV_LOSCALE + badd, 0.0f);
        int lane2 = ((ct_g & 1)*2 + (m >> 3))*16 + q*4 + r;
        int didx = ((T*4 + (ct_g >> 1)) << 9) + lane2*8 + (m & 7);
        if (MODE == 0){
          ushort hi, lo; f2split(v, hi, lo);
          Hho[didx] = hi; Hlo2[didx] = lo;
        } else {
          Hho[didx] = __half_as_ushort(__float2half(v));
          if (ct_g == 7 && m == 15) key[T*16 + q*4 + r] = v;   // exact fp32 sort key (ch 127)
        }
      }
    }
  }
}

// ---------------- sort-pool: coalesced fp32 key read ----------------
__global__ __launch_bounds__(1024) void k_sortpool(const float* __restrict__ keyv, int* __restrict__ sel){
  int g = blockIdx.x, t = threadIdx.x;
  __shared__ unsigned long long key[N_PER];
  __shared__ unsigned long long wred[16];
  float v = keyv[g*N_PER + t];                   // post-relu, v >= 0 -> bits monotone
  key[t] = (((unsigned long long)__float_as_uint(v)) << 10) | (unsigned long long)(N_PER-1 - t);
  __syncthreads();
  for (int r = 0; r < KSP; ++r){
    unsigned long long k = key[t];
    #pragma unroll
    for (int ofs = 32; ofs > 0; ofs >>= 1){
      unsigned long long o2 = __shfl_down(k, ofs, 64);
      if (o2 > k) k = o2;
    }
    if ((t & 63) == 0) wred[t >> 6] = k;
    __syncthreads();
    if (t == 0){
      unsigned long long mm = wred[0];
      #pragma unroll
      for (int j = 1; j < 16; ++j) if (wred[j] > mm) mm = wred[j];
      int idx = (N_PER-1) - (int)(mm & 1023ULL);
      sel[g*KSP + r] = idx;
      key[idx] = 0ULL;
    }
    __syncthreads();
  }
}

// ---------------- head: H3 read from f16 hi plane (frag layout, KC=4) ----------------
__global__ __launch_bounds__(256) void k_head(const ushort* __restrict__ Hhi, const int* __restrict__ sel,
    const float* __restrict__ cwT, const float* __restrict__ cb,
    const float* __restrict__ l1w, const float* __restrict__ l1b,
    const float* __restrict__ l2w, const float* __restrict__ l2b,
    float* __restrict__ out){
  __shared__ __align__(16) float toplds[KSP*HID];
  __shared__ float ypart[8][832];
  __shared__ __align__(16) float yv[832];
  __shared__ float zv[HID];
  int g = blockIdx.x, t = threadIdx.x;
  for (int e = t; e < KSP*HID; e += 256){
    int tt = e >> 7, c = e & 127;
    int n = g*N_PER + sel[g*KSP + tt];
    int idx = ((n >> 4)*4 + (c >> 5))*512 + (((c & 31) >> 3)*16 + (n & 15))*8 + (c & 7);
    toplds[e] = __half2float(__ushort_as_half(Hhi[idx]));
  }
  __syncthreads();
  int o = t & 31, cch = t >> 5;
  float acc[26];
  #pragma unroll
  for (int th = 0; th < 26; ++th) acc[th] = 0.0f;
  for (int c = cch*16; c < cch*16 + 16; ++c){
    float tcol[KSP];
    #pragma unroll
    for (int tt = 0; tt < KSP; ++tt) tcol[tt] = toplds[tt*HID + c];
    float w5[5];
    #pragma unroll
    for (int s = 0; s < 5; ++s) w5[s] = cwT[(c*5 + s)*32 + o];
    #pragma unroll
    for (int th = 0; th < 26; ++th){
      float a2 = acc[th];
      #pragma unroll
      for (int s = 0; s < 5; ++s) a2 += tcol[th + s]*w5[s];
      acc[th] = a2;
    }
  }
  #pragma unroll
  for (int th = 0; th < 26; ++th) ypart[cch][o*26 + th] = acc[th];
  __syncthreads();
  for (int idx = t; idx < 832; idx += 256){
    float s2 = 0.0f;
    #pragma unroll
    for (int j = 0; j < 8; ++j) s2 += ypart[j][idx];
    yv[idx] = fmaxf(s2 + cb[idx / 26], 0.0f);
  }
  __syncthreads();
  if (t < HID){
    float a3 = l1b[t];
    const float4* wr4 = (const float4*)&l1w[t*832];
    const float4* yr4 = (const float4*)yv;
    #pragma unroll 4
    for (int k = 0; k < 208; ++k){
      float4 wv = wr4[k]; float4 yq = yr4[k];
      a3 += wv.x*yq.x + wv.y*yq.y + wv.z*yq.z + wv.w*yq.w;
    }
    zv[t] = fmaxf(a3, 0.0f);
  }
  __syncthreads();
  if (t < OUT_DIM){
    float a4 = l2b[t];
    for (int j = 0; j < HID; ++j) a4 += zv[j]*l2w[t*HID + j];
    out[g*OUT_DIM + t] = a4;
  }
}

extern "C" void kernel_launch(void* const* d_in, const int* in_sizes, int n_in,
                              void* d_out, int out_size, void* d_ws, size_t ws_size,
                              hipStream_t stream){
  const float* x   = (const float*)d_in[0];
  const int*   ei  = (const int*)d_in[1];
  const float* wl1 = (const float*)d_in[3];
  const float* b1  = (const float*)d_in[4];
  const float* wr1 = (const float*)d_in[5];
  const float* wl2 = (const float*)d_in[6];
  const float* b2  = (const float*)d_in[7];
  const float* wr2 = (const float*)d_in[8];
  const float* wl3 = (const float*)d_in[9];
  const float* b3  = (const float*)d_in[10];
  const float* wr3 = (const float*)d_in[11];
  const float* cw  = (const float*)d_in[12];
  const float* cb  = (const float*)d_in[13];
  const float* l1w = (const float*)d_in[14];
  const float* l1b = (const float*)d_in[15];
  const float* l2w = (const float*)d_in[16];
  const float* l2b = (const float*)d_in[17];
  float* out = (float*)d_out;
  const int* esrc = ei;
  const int* edst = ei + N_EDGES;

  char* p = (char*)d_ws;
  auto alloc = [&](size_t bytes)->char*{ char* r = p; p += (bytes + 255) & ~(size_t)255; return r; };
  int*    row_ptr = (int*)alloc((size_t)(N_NODES+1)*4);
  float*  dinv    = (float*)alloc((size_t)N_NODES*4);
  ushort* csr     = (ushort*)alloc((size_t)N_EDGES*2);
  int*    sel     = (int*)alloc((size_t)NGRAPH*KSP*4);
  float*  cwT     = (float*)alloc((size_t)32*HID*5*4);
  float*  keyv    = (float*)alloc((size_t)N_NODES*4);
  ushort* Xhi     = (ushort*)alloc((size_t)N_NODES*32*2);   // 8.4 MB
  ushort* Xlo     = (ushort*)alloc((size_t)N_NODES*32*2);
  ushort* Mhi     = (ushort*)alloc((size_t)N_NODES*HID*2);  // 33.5 MB
  ushort* Mlo     = (ushort*)alloc((size_t)N_NODES*HID*2);
  ushort* Hhi     = (ushort*)alloc((size_t)N_NODES*HID*2);
  ushort* Hlo     = (ushort*)alloc((size_t)N_NODES*HID*2);
  ushort* w1lh = (ushort*)alloc(512*8*2);  ushort* w1ll = (ushort*)alloc(512*8*2);
  ushort* w1rh = (ushort*)alloc(512*8*2);  ushort* w1rl = (ushort*)alloc(512*8*2);
  ushort* w2lh = (ushort*)alloc(512*32*2); ushort* w2ll = (ushort*)alloc(512*32*2);
  ushort* w2rh = (ushort*)alloc(512*32*2); ushort* w2rl = (ushort*)alloc(512*32*2);
  ushort* w3lh = (ushort*)alloc(512*32*2); ushort* w3ll = (ushort*)alloc(512*32*2);
  ushort* w3rh = (ushort*)alloc(512*32*2); ushort* w3rl = (ushort*)alloc(512*32*2);

  k_csr<<<NGRAPH, 1024, 0, stream>>>(esrc, edst, csr, row_ptr, dinv);

  k_pack_x<<<(N_NODES*32)/256, 256, 0, stream>>>(x, Xhi, Xlo);
  k_pack_w<<<(256*32)/256, 256, 0, stream>>>(wl1, wr1, w1lh, w1ll, w1rh, w1rl, 1, IN_CH);
  k_pack_w<<<(256*128)/256, 256, 0, stream>>>(wl2, wr2, w2lh, w2ll, w2rh, w2rl, 4, 128);
  k_pack_w<<<(256*128)/256, 256, 0, stream>>>(wl3, wr3, w3lh, w3ll, w3rh, w3rl, 4, 128);
  k_transpose_cw<<<(32*HID*5 + 255)/256, 256, 0, stream>>>(cw, cwT);

  const int GB = N_NODES/64;       // 2048 gemm blocks (4 row-tiles each)

  // layer 1: M1 = mean(x_nb); h1 = relu(M1@Wl1 + x@Wr1 + b1)  (K padded to 32)
  k_gather<<<NGRAPH*2, 1024, 0, stream>>>(Xhi, Xlo, Mhi, Mlo, row_ptr, csr, dinv, 1);
  k_gemm<1,0><<<GB, 256, 0, stream>>>(Mhi, Mlo, Xhi, Xlo,
      w1lh, w1ll, w1rh, w1rl, b1, Hhi, Hlo, nullptr);
  // layer 2 (in-place h: block reads only its own rows as A before its epilogue writes)
  k_gather<<<NGRAPH*8, 1024, 0, stream>>>(Hhi, Hlo, Mhi, Mlo, row_ptr, csr, dinv, 4);
  k_gemm<4,0><<<GB, 256, 0, stream>>>(Mhi, Mlo, Hhi, Hlo,
      w2lh, w2ll, w2rh, w2rl, b2, Hhi, Hlo, nullptr);
  // layer 3 -> f16 hi plane (head input) + exact fp32 sort key (channel 127)
  k_gather<<<NGRAPH*8, 1024, 0, stream>>>(Hhi, Hlo, Mhi, Mlo, row_ptr, csr, dinv, 4);
  k_gemm<4,1><<<GB, 256, 0, stream>>>(Mhi, Mlo, Hhi, Hlo,
      w3lh, w3ll, w3rh, w3rl, b3, Hhi, nullptr, keyv);

  k_sortpool<<<NGRAPH, 1024, 0, stream>>>(keyv, sel);
  k_head<<<NGRAPH, 256, 0, stream>>>(Hhi, sel, cwT, cb, l1w, l1b, l2w, l2b, out);
}